// Round 13
// baseline (3747.345 us; speedup 1.0000x reference)
//
#include <hip/hip_runtime.h>
#include <math.h>
#include <string.h>

// ---------------- model constants ----------------
#define BB    16
#define LEc   720
#define LDc   144
#define PREDc 96
#define DMc   512
#define NHc   8
#define DHc   64
#define MFc   256
#define FFc   2048
#define NEc   (BB*LEc)   // 11520
#define NDc   (BB*LDc)   // 2304
#define BHc   (BB*NHc)   // 128
#define KSn   ((size_t)BHc*MFc)       // 32,768

typedef unsigned int u32;
typedef unsigned short u16;
typedef unsigned long long u64;
typedef unsigned __int128 u128;

typedef short bfx8 __attribute__((ext_vector_type(8)));
typedef float fx4  __attribute__((ext_vector_type(4)));
typedef unsigned short u16x4 __attribute__((ext_vector_type(4)));

// =====================================================================
// Host-side exact replication of numpy default_rng(seed) -> PCG64 ->
// ziggurat standard_normal, plus LAPACK-convention Householder QR.
// =====================================================================
struct NpSeedSeq {
  u32 pool[4];
  u32 hc;
  u32 hashmix(u32 v){ v ^= hc; hc *= 0x931e8875u; v *= hc; v ^= v >> 16; return v; }
  static u32 mixv(u32 x, u32 y){ u32 r = x*0xca01f9ddu - y*0x4973f715u; r ^= r >> 16; return r; }
  NpSeedSeq(u32 entropy){
    hc = 0x43b0d7e5u;
    for (int i=0;i<4;i++) pool[i] = hashmix(i==0 ? entropy : 0u);
    for (int s=0;s<4;s++)
      for (int d=0;d<4;d++)
        if (s!=d) pool[d] = mixv(pool[d], hashmix(pool[s]));
  }
  void generate8(u32* w){
    u32 h = 0x8b51f9ddu;
    for (int i=0;i<8;i++){
      u32 v = pool[i & 3];
      v ^= h; h *= 0x58f38dedu; v *= h; v ^= v >> 16;
      w[i] = v;
    }
  }
};

struct NpPCG64 {
  u128 state, inc;
  static u128 pcgmult(){ return ((u128)0x2360ed051fc65da4ull << 64) | 0x4385df649fccf645ull; }
  void step(){ state = state * pcgmult() + inc; }
  NpPCG64(u32 seed){
    NpSeedSeq ss(seed);
    u32 w[8]; ss.generate8(w);
    u64 v0 = (u64)w[0] | ((u64)w[1] << 32);
    u64 v1 = (u64)w[2] | ((u64)w[3] << 32);
    u64 v2 = (u64)w[4] | ((u64)w[5] << 32);
    u64 v3 = (u64)w[6] | ((u64)w[7] << 32);
    u128 initstate = ((u128)v0 << 64) | v1;
    u128 initseq   = ((u128)v2 << 64) | v3;
    state = 0; inc = (initseq << 1) | 1;
    step(); state += initstate; step();
  }
  u64 next64(){
    step();
    u64 hi = (u64)(state >> 64), lo = (u64)state;
    u32 rot = (u32)(state >> 122);
    u64 x = hi ^ lo;
    return (x >> rot) | (x << ((64u - rot) & 63u));
  }
  double nextDouble(){ return (double)(next64() >> 11) * (1.0/9007199254740992.0); }
};

static u64    zki[256];
static double zwi[256], zfi[256];
static void init_zig(){
  const double r  = 3.6541528853610087963519472518;
  const double mq = 4503599627370496.0; // 2^52
  double fr = exp(-0.5*r*r);
  double vv = r*fr + sqrt(M_PI*0.5)*erfc(r/sqrt(2.0));
  double q  = vv/fr;
  zki[0] = (u64)((r/q)*mq);
  zki[1] = 0;
  zwi[0] = q/mq; zwi[255] = r/mq;
  zfi[0] = 1.0;  zfi[255] = fr;
  double tn = r, dn = r;
  for (int i=254;i>=1;i--){
    dn = sqrt(-2.0*log(vv/dn + exp(-0.5*dn*dn)));
    zki[i+1] = (u64)((dn/tn)*mq);
    tn = dn;
    zfi[i] = exp(-0.5*dn*dn);
    zwi[i] = dn/mq;
  }
}

static double std_normal(NpPCG64& g){
  const double nor_r = 3.6541528853610087963519472518;
  const double inv_r = 0.27366123732975827203338247596;
  for(;;){
    u64 rr = g.next64();
    int idx  = (int)(rr & 0xff); rr >>= 8;
    int sign = (int)(rr & 1);
    u64 rabs = (rr >> 1) & 0x000fffffffffffffULL;
    double x = (double)rabs * zwi[idx];
    if (sign) x = -x;
    if (rabs < zki[idx]) return x;
    if (idx == 0){
      double xx, yy;
      do {
        xx = -inv_r * log1p(-g.nextDouble());
        yy = -log1p(-g.nextDouble());
      } while (yy + yy <= xx*xx);
      return ((rabs >> 8) & 1) ? -(nor_r + xx) : (nor_r + xx);
    } else {
      if ((zfi[idx-1]-zfi[idx]) * g.nextDouble() + zfi[idx] < exp(-0.5*x*x)) return x;
    }
  }
}

// Householder QR (LAPACK dgeqrf/dorgqr convention), A,Q row-major 64x64.
static void qr_q64(double* A, double* Q){
  const int n = 64;
  static double V[64][64];
  static double tau[64];
  for (int j=0;j<n;j++){
    double alpha = A[j*n+j];
    double xn2 = 0;
    for (int i=j+1;i<n;i++) xn2 += A[i*n+j]*A[i*n+j];
    double xnorm = sqrt(xn2);
    if (xnorm == 0.0){
      tau[j] = 0.0;
      for (int i=j;i<n;i++) V[j][i] = (i==j) ? 1.0 : 0.0;
      continue;
    }
    double beta = -copysign(hypot(alpha, xnorm), alpha);
    double tj = (beta - alpha)/beta;
    double sc = 1.0/(alpha - beta);
    tau[j] = tj;
    V[j][j] = 1.0;
    for (int i=j+1;i<n;i++) V[j][i] = A[i*n+j]*sc;
    A[j*n+j] = beta;
    for (int c=j+1;c<n;c++){
      double w = 0;
      for (int i=j;i<n;i++) w += V[j][i]*A[i*n+c];
      w *= tj;
      for (int i=j;i<n;i++) A[i*n+c] -= V[j][i]*w;
    }
  }
  for (int i=0;i<n;i++) for (int c=0;c<n;c++) Q[i*n+c] = (i==c)?1.0:0.0;
  for (int j=n-1;j>=0;j--){
    double tj = tau[j];
    if (tj == 0.0) continue;
    for (int c=0;c<n;c++){
      double w = 0;
      for (int i=j;i<n;i++) w += V[j][i]*Q[i*n+c];
      w *= tj;
      for (int i=j;i<n;i++) Q[i*n+c] -= V[j][i]*w;
    }
  }
}

static void build_orf(u32 seed, float* outp){ // outp: [256*64]
  NpPCG64 g(seed);
  static double mat[MFc][DHc];
  static double A[64*64], Q[64*64];
  for (int blk=0; blk<4; blk++){
    for (int i=0;i<4096;i++) A[i] = std_normal(g);
    qr_q64(A, Q);
    for (int r=0;r<64;r++)
      for (int c=0;c<64;c++)
        mat[blk*64 + r][c] = Q[c*64 + r];   // block.T
  }
  for (int r=0;r<MFc;r++){
    double ss = 0;
    double row[64];
    for (int c=0;c<64;c++){ row[c] = std_normal(g); ss += row[c]*row[c]; }
    double nrm = sqrt(ss);
    for (int c=0;c<64;c++) outp[r*64 + c] = (float)(nrm * mat[r][c]);
  }
}

static void build_all_proj(float* h){
  init_zig();
  const u32 seeds[4] = {0u, 1u, 10u, 11u};
  for (int s=0;s<4;s++) build_orf(seeds[s], h + (size_t)s*MFc*DHc);
}

// =====================================================================
// Device helpers
// =====================================================================
__device__ __forceinline__ u16 f2bf(float x){
  u32 u = __builtin_bit_cast(u32, x);
  u32 r = (u + 0x7FFFu + ((u >> 16) & 1u)) >> 16;
  return (u16)r;
}
__device__ __forceinline__ float bf2f(u16 x){
  return __builtin_bit_cast(float, ((u32)x) << 16);
}

// =====================================================================
// Device kernels
// =====================================================================

__global__ __launch_bounds__(256) void k_zero(float* __restrict__ p, int n){
  int i = blockIdx.x*256 + threadIdx.x;
  if (i < n) p[i] = 0.f;
}

__global__ __launch_bounds__(256) void k_projbf(const float* __restrict__ p, u16* __restrict__ pb, int n){
  int i = blockIdx.x*256 + threadIdx.x;
  if (i < n) pb[i] = f2bf(p[i]);
}

// sinusoidal PE table [720][512] (decoder uses rows 0..143, same formula)
__global__ __launch_bounds__(256) void k_petab(float* __restrict__ pe){
  int idx = blockIdx.x*256 + threadIdx.x;      // 720*512
  int d = idx & 511; int l = idx >> 9;
  int i2 = d & ~1;
  float div = expf((float)i2 * (-0.017988946039015984f)); // -ln(10000)/512
  float ang = (float)l * div;
  pe[idx] = (d & 1) ? cosf(ang) : sinf(ang);
}

// weight transpose + cast: WT[n][k] = bf16(W[k][n])
__global__ __launch_bounds__(256) void k_wtr(const float* __restrict__ W, u16* __restrict__ WT,
                                             int K, int N){
  __shared__ float t[32][33];
  int kb = blockIdx.x*32, nb = blockIdx.y*32;
  int tx = threadIdx.x & 31, ty = threadIdx.x >> 5;
  #pragma unroll
  for (int p=0;p<4;p++)
    t[ty + p*8][tx] = W[(size_t)(kb + ty + p*8)*N + nb + tx];
  __syncthreads();
  #pragma unroll
  for (int p=0;p<4;p++)
    WT[(size_t)(nb + ty + p*8)*K + kb + tx] = f2bf(t[tx][ty + p*8]);
}

// RevIN stats: one block per (b,c)
__global__ __launch_bounds__(64) void k_meanstd(const float* __restrict__ x,
                                                float* __restrict__ means, float* __restrict__ stdev){
  int bc = blockIdx.x; int b = bc/7, c = bc%7;
  int t = threadIdx.x;
  float s=0;
  for (int l=t; l<LEc; l+=64) s += x[((size_t)b*LEc+l)*7 + c];
  for (int o=32;o;o>>=1) s += __shfl_down(s,o);
  s = __shfl(s,0);
  float mu = s / (float)LEc;
  float v=0;
  for (int l=t; l<LEc; l+=64){ float d = x[((size_t)b*LEc+l)*7+c]-mu; v += d*d; }
  for (int o=32;o;o>>=1) v += __shfl_down(v,o);
  if (t==0){ means[bc]=mu; stdev[bc]=sqrtf(v/(float)LEc + 1e-5f); }
}

// token embed: circular conv(k=3) + PE table + timeF linear
__global__ __launch_bounds__(256) void k_embed(const float* __restrict__ x, const float* __restrict__ mark,
    const float* __restrict__ convw, const float* __restrict__ timew, const float* __restrict__ pe,
    const float* __restrict__ means, const float* __restrict__ stdev,
    int L, int donorm, float* __restrict__ outp)
{
  size_t idx = (size_t)blockIdx.x*256 + threadIdx.x;
  size_t total = (size_t)BB*L*DMc;
  if (idx >= total) return;
  int d = (int)(idx % DMc); size_t bl = idx / DMc; int l = (int)(bl % L); int b = (int)(bl / L);
  int lm = (l==0)? L-1 : l-1;
  int lp = (l==L-1)? 0 : l+1;
  float acc = pe[(size_t)l*DMc + d];
  const float* xb = x + (size_t)b*L*7;
  #pragma unroll
  for (int c=0;c<7;c++){
    float v0 = xb[(size_t)lm*7+c], v1 = xb[(size_t)l*7+c], v2 = xb[(size_t)lp*7+c];
    if (donorm){
      float mu = means[b*7+c], sd = stdev[b*7+c];
      v0=(v0-mu)/sd; v1=(v1-mu)/sd; v2=(v2-mu)/sd;
    }
    acc += v0*convw[(0*7+c)*DMc+d] + v1*convw[(1*7+c)*DMc+d] + v2*convw[(2*7+c)*DMc+d];
  }
  const float* mb = mark + ((size_t)b*L + l)*4;
  #pragma unroll
  for (int t=0;t<4;t++) acc += mb[t]*timew[t*DMc+d];
  outp[idx] = acc;
}

// ------------------ bf16 MFMA GEMM (XCD-swizzled) ------------------
template<int A_BF16, int OUT_BF16, int GELU>
__global__ __launch_bounds__(256) void k_gemm_mfma(
    const void* __restrict__ Ap, const u16* __restrict__ WT,
    const float* __restrict__ bias, void* __restrict__ Cp,
    int M, int N, int K)
{
  __shared__ u16 As[128][40];  // [row][k], +8 pad
  __shared__ u16 Bs[128][40];  // [col][k], +8 pad
  int nb = N >> 7;
  int bid = blockIdx.x;
  int nwg = gridDim.x;
  if (!(nwg & 7)) bid = ((bid & 7) * (nwg >> 3)) + (bid >> 3);   // XCD-contiguous row-bands
  int bx = bid % nb, by = bid / nb;
  int row0 = by << 7, col0 = bx << 7;
  int tid = threadIdx.x;
  int wid = tid >> 6, lane = tid & 63;
  int wr = (wid >> 1) * 64, wc = (wid & 1) * 64;
  int l15 = lane & 15, lg = lane >> 4;
  fx4 acc[4][4];
  #pragma unroll
  for (int i=0;i<4;i++)
    #pragma unroll
    for (int j=0;j<4;j++)
      #pragma unroll
      for (int r=0;r<4;r++) acc[i][j][r] = 0.f;

  for (int k0 = 0; k0 < K; k0 += 32){
    if (A_BF16){
      const u16* A = (const u16*)Ap;
      #pragma unroll
      for (int p=0;p<2;p++){
        int idx = tid + (p<<8);
        int r = idx >> 2, kq = (idx & 3) << 3;
        *(bfx8*)&As[r][kq] = *(const bfx8*)(A + (size_t)(row0+r)*K + k0 + kq);
      }
    } else {
      const float* A = (const float*)Ap;
      #pragma unroll
      for (int p=0;p<4;p++){
        int idx = tid + (p<<8);
        int r = idx >> 3, kq = (idx & 7) << 2;
        float4 v = *(const float4*)(A + (size_t)(row0+r)*K + k0 + kq);
        u32 lo = (u32)f2bf(v.x) | ((u32)f2bf(v.y) << 16);
        u32 hi = (u32)f2bf(v.z) | ((u32)f2bf(v.w) << 16);
        *(u32*)&As[r][kq]   = lo;
        *(u32*)&As[r][kq+2] = hi;
      }
    }
    #pragma unroll
    for (int p=0;p<2;p++){
      int idx = tid + (p<<8);
      int c = idx >> 2, kq = (idx & 3) << 3;
      *(bfx8*)&Bs[c][kq] = *(const bfx8*)(WT + (size_t)(col0+c)*K + k0 + kq);
    }
    __syncthreads();
    int kg = lg << 3;
    bfx8 af[4], bf[4];
    #pragma unroll
    for (int i=0;i<4;i++) af[i] = *(const bfx8*)&As[wr + i*16 + l15][kg];
    #pragma unroll
    for (int j=0;j<4;j++) bf[j] = *(const bfx8*)&Bs[wc + j*16 + l15][kg];
    #pragma unroll
    for (int i=0;i<4;i++)
      #pragma unroll
      for (int j=0;j<4;j++)
        acc[i][j] = __builtin_amdgcn_mfma_f32_16x16x32_bf16(af[i], bf[j], acc[i][j], 0, 0, 0);
    __syncthreads();
  }
  #pragma unroll
  for (int j=0;j<4;j++){
    int col = col0 + wc + j*16 + l15;
    float bv = bias ? bias[col] : 0.f;
    #pragma unroll
    for (int i=0;i<4;i++){
      #pragma unroll
      for (int r=0;r<4;r++){
        int row = row0 + wr + i*16 + (lg<<2) + r;
        float v = acc[i][j][r] + bv;
        if (GELU) v = 0.5f*v*(1.0f + erff(v*0.7071067811865475f));
        if (OUT_BF16) ((u16*)Cp)[(size_t)row*N + col] = f2bf(v);
        else          ((float*)Cp)[(size_t)row*N + col] = v;
      }
    }
  }
}

static inline void gemm_bf(const void* A, const u16* WT, const float* bias, void* C,
                           int M, int N, int K, int abf, int obf, int gelu, hipStream_t st){
  dim3 g((N/128)*(M/128));
  if (abf && obf && gelu)  k_gemm_mfma<1,1,1><<<g,256,0,st>>>(A,WT,bias,C,M,N,K);
  else if (abf && obf)     k_gemm_mfma<1,1,0><<<g,256,0,st>>>(A,WT,bias,C,M,N,K);
  else if (abf)            k_gemm_mfma<1,0,0><<<g,256,0,st>>>(A,WT,bias,C,M,N,K);
  else if (gelu)           k_gemm_mfma<0,1,1><<<g,256,0,st>>>(A,WT,bias,C,M,N,K);
  else if (obf)            k_gemm_mfma<0,1,0><<<g,256,0,st>>>(A,WT,bias,C,M,N,K);
  else                     k_gemm_mfma<0,0,0><<<g,256,0,st>>>(A,WT,bias,C,M,N,K);
}

// ------------------ fused QKV GEMM: A f32, WT = NSEG contiguous [512][K] weights,
// output seg s -> Cs[row][512] bf16. N = NSEG*512. ------------------
template<int NSEG>
__global__ __launch_bounds__(256) void k_gemm_qkv(
    const float* __restrict__ Ap, const u16* __restrict__ WT,
    u16* __restrict__ C0, u16* __restrict__ C1, u16* __restrict__ C2,
    int M, int K)
{
  const int N = NSEG*512;
  __shared__ u16 As[128][40];
  __shared__ u16 Bs[128][40];
  int nb = N >> 7;
  int bid = blockIdx.x;
  int nwg = gridDim.x;
  if (!(nwg & 7)) bid = ((bid & 7) * (nwg >> 3)) + (bid >> 3);
  int bx = bid % nb, by = bid / nb;
  int row0 = by << 7, col0 = bx << 7;
  int tid = threadIdx.x;
  int wid = tid >> 6, lane = tid & 63;
  int wr = (wid >> 1) * 64, wc = (wid & 1) * 64;
  int l15 = lane & 15, lg = lane >> 4;
  fx4 acc[4][4];
  #pragma unroll
  for (int i=0;i<4;i++)
    #pragma unroll
    for (int j=0;j<4;j++)
      #pragma unroll
      for (int r=0;r<4;r++) acc[i][j][r] = 0.f;

  for (int k0 = 0; k0 < K; k0 += 32){
    #pragma unroll
    for (int p=0;p<4;p++){
      int idx = tid + (p<<8);
      int r = idx >> 3, kq = (idx & 7) << 2;
      float4 v = *(const float4*)(Ap + (size_t)(row0+r)*K + k0 + kq);
      u32 lo = (u32)f2bf(v.x) | ((u32)f2bf(v.y) << 16);
      u32 hi = (u32)f2bf(v.z) | ((u32)f2bf(v.w) << 16);
      *(u32*)&As[r][kq]   = lo;
      *(u32*)&As[r][kq+2] = hi;
    }
    #pragma unroll
    for (int p=0;p<2;p++){
      int idx = tid + (p<<8);
      int c = idx >> 2, kq = (idx & 3) << 3;
      *(bfx8*)&Bs[c][kq] = *(const bfx8*)(WT + (size_t)(col0+c)*K + k0 + kq);
    }
    __syncthreads();
    int kg = lg << 3;
    bfx8 af[4], bf[4];
    #pragma unroll
    for (int i=0;i<4;i++) af[i] = *(const bfx8*)&As[wr + i*16 + l15][kg];
    #pragma unroll
    for (int j=0;j<4;j++) bf[j] = *(const bfx8*)&Bs[wc + j*16 + l15][kg];
    #pragma unroll
    for (int i=0;i<4;i++)
      #pragma unroll
      for (int j=0;j<4;j++)
        acc[i][j] = __builtin_amdgcn_mfma_f32_16x16x32_bf16(af[i], bf[j], acc[i][j], 0, 0, 0);
    __syncthreads();
  }
  int seg = col0 >> 9;
  u16* Cs = (seg==0) ? C0 : (seg==1) ? C1 : C2;
  int cb = col0 - (seg << 9);
  #pragma unroll
  for (int j=0;j<4;j++){
    int col = cb + wc + j*16 + l15;
    #pragma unroll
    for (int i=0;i<4;i++){
      #pragma unroll
      for (int r=0;r<4;r++){
        int row = row0 + wr + i*16 + (lg<<2) + r;
        Cs[(size_t)row*512 + col] = f2bf(acc[i][j][r]);
      }
    }
  }
}

// per-row max_m of xd, MFMA version. out rowmax[bh][n] scaled by 64^-0.25.
__global__ __launch_bounds__(256) void k_rowmax_mfma(const u16* __restrict__ Kb,
    const u16* __restrict__ projbf, float* __restrict__ rowmax, int n)
{
  int ntile = n >> 4;
  int rt = blockIdx.x % ntile, bh = blockIdx.x / ntile;
  int b = bh >> 3, h = bh & 7;
  int row0 = rt << 4;
  int tid = threadIdx.x, w = tid >> 6, lane = tid & 63;
  int l15 = lane & 15, lg = lane >> 4;
  __shared__ u16 qs[16][72];
  __shared__ float xds[16][264];
  __shared__ float red[16][16];
  for (int i = tid; i < 16*16; i += 256){
    int r = i >> 4, dq = (i & 15)*4;
    *(u16x4*)&qs[r][dq] = *(const u16x4*)(Kb + ((size_t)b*n + row0 + r)*DMc + h*64 + dq);
  }
  __syncthreads();
  #pragma unroll
  for (int mt=0; mt<4; mt++){
    int m16 = (w*4+mt)*16;
    fx4 a2 = {0.f,0.f,0.f,0.f};
    #pragma unroll
    for (int ks=0; ks<2; ks++){
      bfx8 af = *(const bfx8*)&qs[l15][ks*32 + lg*8];
      bfx8 bf = *(const bfx8*)(projbf + (size_t)(m16+l15)*64 + ks*32 + lg*8);
      a2 = __builtin_amdgcn_mfma_f32_16x16x32_bf16(af, bf, a2, 0, 0, 0);
    }
    #pragma unroll
    for (int r=0;r<4;r++)
      xds[lg*4+r][m16+l15] = a2[r];
  }
  __syncthreads();
  { int r = tid >> 4, s = tid & 15;
    float mx = -1e30f;
    #pragma unroll
    for (int j=0;j<16;j++) mx = fmaxf(mx, xds[r][s*16+j]);
    red[r][s] = mx; }
  __syncthreads();
  if (tid < 16){
    float mx = -1e30f;
    #pragma unroll
    for (int j=0;j<16;j++) mx = fmaxf(mx, red[tid][j]);
    rowmax[(size_t)bh*n + row0 + tid] = mx * 0.35355339059327373f;
  }
}

__global__ __launch_bounds__(256) void k_stab(const float* __restrict__ rowmax, float* __restrict__ stab, int n){
  int bh = blockIdx.x; int tid = threadIdx.x;
  float mx = -1e30f;
  for (int i=tid;i<n;i+=256) mx = fmaxf(mx, rowmax[(size_t)bh*n+i]);
  __shared__ float red[4];
  for (int o=32;o;o>>=1) mx = fmaxf(mx, __shfl_xor(mx,o));
  if ((tid&63)==0) red[tid>>6]=mx;
  __syncthreads();
  if (tid==0) stab[bh] = fmaxf(fmaxf(red[0],red[1]),fmaxf(red[2],red[3]));
}

// V transpose per head: Vt[bh][d][n] bf16 from Vb[b*n][512]
__global__ __launch_bounds__(256) void k_vtr(const u16* __restrict__ Vb, u16* __restrict__ Vt, int n){
  int nt = n >> 4;
  int blk = blockIdx.x; int t16 = blk % nt; int bh = blk / nt;
  int b = bh >> 3, h = bh & 7;
  int n0 = t16 << 4;
  int t = threadIdx.x;
  __shared__ u16 vt[16][72];
  { int r = t >> 4, d0 = (t & 15) * 4;
    *(u16x4*)&vt[r][d0] = *(const u16x4*)(Vb + ((size_t)b*n + n0 + r)*DMc + h*64 + d0); }
  __syncthreads();
  { int d = t >> 2, j = t & 3;
    u16x4 o;
    o.x = vt[j*4+0][d]; o.y = vt[j*4+1][d]; o.z = vt[j*4+2][d]; o.w = vt[j*4+3][d];
    *(u16x4*)(Vt + ((size_t)bh*64 + d)*(size_t)n + n0 + j*4) = o; }
}

// Fused K feature-map + KV accumulation + KS, all-MFMA, m-split x2.
// grid = BHc*2*2 (bh x d-half x m-half). Disjoint KVT/KS writes per block.
__global__ __launch_bounds__(256) void k_kvfull(const u16* __restrict__ Kb,
    const u16* __restrict__ Vt, const u16* __restrict__ projbf, const float* __restrict__ stab,
    u16* __restrict__ KVT, float* __restrict__ KS, int n)
{
  int mh = blockIdx.x & 1;
  int rest = blockIdx.x >> 1;
  int dh = (rest & 1) * 32;
  int bh = rest >> 1;
  int b = bh >> 3, h = bh & 7;
  int tid = threadIdx.x, w = tid >> 6, lane = tid & 63;
  int l15 = lane & 15, lg = lane >> 4;
  int m0 = mh * 128;
  float sb = stab[bh];
  __shared__ u16 ksb[32][72];
  __shared__ u16 kpT[128][40];
  __shared__ u16 vsb[32][40];
  __shared__ float dgs[32];
  fx4 kv[2][2];
  #pragma unroll
  for (int i=0;i<2;i++)
    #pragma unroll
    for (int j=0;j<2;j++)
      #pragma unroll
      for (int r=0;r<4;r++) kv[i][j][r] = 0.f;
  float ksl[2] = {0.f,0.f};
  int nchunks = (n + 31) >> 5;
  for (int c=0; c<nchunks; c++){
    int n0 = c << 5;
    for (int i = tid; i < 32*16; i += 256){
      int r = i >> 4, dq = (i & 15) * 4;
      u16x4 v = {0,0,0,0};
      if (n0 + r < n) v = *(const u16x4*)(Kb + ((size_t)b*n + n0 + r)*DMc + h*64 + dq);
      *(u16x4*)&ksb[r][dq] = v;
    }
    for (int i = tid; i < 32*8; i += 256){
      int r = i >> 3, nq4 = (i & 7) * 4;
      u16x4 v = {0,0,0,0};
      const u16* src = Vt + ((size_t)bh*64 + dh + r)*(size_t)n + n0 + nq4;
      if (n0 + nq4 + 3 < n) v = *(const u16x4*)src;
      else { for (int j=0;j<4;j++) if (n0+nq4+j < n) v[j] = src[j]; }
      *(u16x4*)&vsb[r][nq4] = v;
    }
    __syncthreads();
    { // parallel diag: 8 threads per row, shfl-reduce
      int r = tid >> 3, j = tid & 7;
      float dg = 0;
      #pragma unroll
      for (int q=0;q<8;q++){ float kd = bf2f(ksb[r][j*8+q]); dg = fmaf(kd,kd,dg); }
      dg += __shfl_down(dg,4); dg += __shfl_down(dg,2); dg += __shfl_down(dg,1);
      if (j == 0) dgs[r] = dg * 0.0625f;
    }
    __syncthreads();
    #pragma unroll
    for (int mt=0; mt<2; mt++){
      int ml = (w*2 + mt)*16;            // local m tile [0,128)
      int mg = m0 + ml;                  // global m
      #pragma unroll
      for (int nt=0; nt<2; nt++){
        fx4 a2 = {0.f,0.f,0.f,0.f};
        #pragma unroll
        for (int ks=0; ks<2; ks++){
          bfx8 af = *(const bfx8*)&ksb[nt*16 + l15][ks*32 + lg*8];
          bfx8 bf = *(const bfx8*)(projbf + (size_t)(mg + l15)*64 + ks*32 + lg*8);
          a2 = __builtin_amdgcn_mfma_f32_16x16x32_bf16(af, bf, a2, 0, 0, 0);
        }
        #pragma unroll
        for (int r=0;r<4;r++){
          int nn = nt*16 + lg*4 + r;
          float kp = 0.f;
          if (n0 + nn < n)
            kp = (__expf(a2[r]*0.35355339059327373f - dgs[nn] - sb) + 1e-4f) * 0.0625f;
          ksl[mt] += kp;
          kpT[ml + l15][nn] = f2bf(kp);
        }
      }
    }
    __syncthreads();
    #pragma unroll
    for (int dt=0; dt<2; dt++){
      #pragma unroll
      for (int mt=0; mt<2; mt++){
        bfx8 af = *(const bfx8*)&vsb[dt*16 + l15][lg*8];
        bfx8 bf = *(const bfx8*)&kpT[(w*2+mt)*16 + l15][lg*8];
        kv[dt][mt] = __builtin_amdgcn_mfma_f32_16x16x32_bf16(af, bf, kv[dt][mt], 0, 0, 0);
      }
    }
    __syncthreads();
  }
  if (dh == 0){
    #pragma unroll
    for (int mt=0; mt<2; mt++){
      float v = ksl[mt];
      v += __shfl_xor(v, 16);
      v += __shfl_xor(v, 32);
      if (lg == 0) KS[(size_t)bh*MFc + m0 + (w*2+mt)*16 + l15] = v;
    }
  }
  #pragma unroll
  for (int dt=0; dt<2; dt++)
    #pragma unroll
    for (int mt=0; mt<2; mt++)
      #pragma unroll
      for (int r=0;r<4;r++){
        int d = dh + dt*16 + lg*4 + r;
        int m = m0 + (w*2+mt)*16 + l15;
        KVT[((size_t)bh*64 + d)*MFc + m] = f2bf(kv[dt][mt][r]);
      }
}

// Fused Q feature-map + non-causal attention output, all-MFMA.
__global__ __launch_bounds__(256) void k_attn_mfma(const u16* __restrict__ Qb,
    const u16* __restrict__ projbf, const u16* __restrict__ KVT, const float* __restrict__ KS,
    u16* __restrict__ O, int nq)
{
  int ntile = nq >> 4;
  int rt = blockIdx.x % ntile, bh = blockIdx.x / ntile;
  int b = bh >> 3, h = bh & 7;
  int row0 = rt << 4;
  int tid = threadIdx.x, w = tid >> 6, lane = tid & 63;
  int l15 = lane & 15, lg = lane >> 4;
  __shared__ u16 qs[16][72];
  __shared__ float xds[16][264];
  __shared__ u16 qpl[16][264];
  __shared__ float dgs[16], mxs[16], dns[16];
  __shared__ float red[16][16];
  __shared__ float kss[256];
  for (int i = tid; i < 16*16; i += 256){
    int r = i >> 4, dq = (i & 15)*4;
    *(u16x4*)&qs[r][dq] = *(const u16x4*)(Qb + ((size_t)b*nq + row0 + r)*DMc + h*64 + dq);
  }
  kss[tid] = KS[(size_t)bh*MFc + tid];
  __syncthreads();
  if (tid < 16){
    float dg = 0;
    #pragma unroll 16
    for (int d=0;d<64;d++){ float q = bf2f(qs[tid][d]); dg = fmaf(q,q,dg); }
    dgs[tid] = dg * 0.0625f;
  }
  #pragma unroll
  for (int mt=0; mt<4; mt++){
    int m16 = (w*4+mt)*16;
    fx4 a2 = {0.f,0.f,0.f,0.f};
    #pragma unroll
    for (int ks=0; ks<2; ks++){
      bfx8 af = *(const bfx8*)&qs[l15][ks*32 + lg*8];
      bfx8 bf = *(const bfx8*)(projbf + (size_t)(m16+l15)*64 + ks*32 + lg*8);
      a2 = __builtin_amdgcn_mfma_f32_16x16x32_bf16(af, bf, a2, 0, 0, 0);
    }
    #pragma unroll
    for (int r=0;r<4;r++)
      xds[lg*4+r][m16+l15] = a2[r]*0.35355339059327373f;
  }
  __syncthreads();
  { int r = tid >> 4, s = tid & 15;
    float mx = -1e30f;
    #pragma unroll
    for (int j=0;j<16;j++) mx = fmaxf(mx, xds[r][s*16+j]);
    red[r][s] = mx; }
  __syncthreads();
  if (tid < 16){
    float mx = -1e30f;
    #pragma unroll
    for (int j=0;j<16;j++) mx = fmaxf(mx, red[tid][j]);
    mxs[tid] = mx;
  }
  __syncthreads();
  { int r = tid >> 4, s = tid & 15;
    float dg = dgs[r], mx = mxs[r], pd = 0;
    #pragma unroll
    for (int j=0;j<16;j++){
      int m = s*16+j;
      float v = (__expf(xds[r][m] - dg - mx) + 1e-4f)*0.0625f;
      qpl[r][m] = f2bf(v);
      pd = fmaf(v, kss[m], pd);
    }
    red[r][s] = pd; }
  __syncthreads();
  if (tid < 16){
    float s = 0;
    #pragma unroll
    for (int j=0;j<16;j++) s += red[tid][j];
    dns[tid] = 1.0f / s;
  }
  __syncthreads();
  fx4 a2 = {0.f,0.f,0.f,0.f};
  #pragma unroll
  for (int ks=0; ks<8; ks++){
    bfx8 af = *(const bfx8*)&qpl[l15][ks*32 + lg*8];
    bfx8 bf = *(const bfx8*)(KVT + ((size_t)bh*64 + w*16 + l15)*MFc + ks*32 + lg*8);
    a2 = __builtin_amdgcn_mfma_f32_16x16x32_bf16(af, bf, a2, 0, 0, 0);
  }
  #pragma unroll
  for (int r=0;r<4;r++){
    int row = lg*4 + r;
    O[((size_t)b*nq + row0 + row)*DMc + h*64 + w*16 + l15] = f2bf(a2[r]*dns[row]);
  }
}

// Feature-map rows -> P[bh][n][256] bf16 (for causal attention), all-MFMA.
template<int ISQ>
__global__ __launch_bounds__(256) void k_fmap_mfma(const u16* __restrict__ Xb,
    const u16* __restrict__ projbf, const float* __restrict__ stab,
    u16* __restrict__ P, int n)
{
  int ntile = n >> 4;
  int rt = blockIdx.x % ntile, bh = blockIdx.x / ntile;
  int b = bh >> 3, h = bh & 7;
  int row0 = rt << 4;
  int tid = threadIdx.x, w = tid >> 6, lane = tid & 63;
  int l15 = lane & 15, lg = lane >> 4;
  __shared__ u16 qs[16][72];
  __shared__ float xds[16][264];
  __shared__ float dgs[16], mxs[16];
  __shared__ float red[16][16];
  for (int i = tid; i < 16*16; i += 256){
    int r = i >> 4, dq = (i & 15)*4;
    *(u16x4*)&qs[r][dq] = *(const u16x4*)(Xb + ((size_t)b*n + row0 + r)*DMc + h*64 + dq);
  }
  __syncthreads();
  if (tid < 16){
    float dg = 0;
    #pragma unroll 16
    for (int d=0;d<64;d++){ float q = bf2f(qs[tid][d]); dg = fmaf(q,q,dg); }
    dgs[tid] = dg * 0.0625f;
  }
  #pragma unroll
  for (int mt=0; mt<4; mt++){
    int m16 = (w*4+mt)*16;
    fx4 a2 = {0.f,0.f,0.f,0.f};
    #pragma unroll
    for (int ks=0; ks<2; ks++){
      bfx8 af = *(const bfx8*)&qs[l15][ks*32 + lg*8];
      bfx8 bf = *(const bfx8*)(projbf + (size_t)(m16+l15)*64 + ks*32 + lg*8);
      a2 = __builtin_amdgcn_mfma_f32_16x16x32_bf16(af, bf, a2, 0, 0, 0);
    }
    #pragma unroll
    for (int r=0;r<4;r++)
      xds[lg*4+r][m16+l15] = a2[r]*0.35355339059327373f;
  }
  __syncthreads();
  if (ISQ){
    { int r = tid >> 4, s = tid & 15;
      float mx = -1e30f;
      #pragma unroll
      for (int j=0;j<16;j++) mx = fmaxf(mx, xds[r][s*16+j]);
      red[r][s] = mx; }
    __syncthreads();
    if (tid < 16){
      float mx = -1e30f;
      #pragma unroll
      for (int j=0;j<16;j++) mx = fmaxf(mx, red[tid][j]);
      mxs[tid] = mx;
    }
    __syncthreads();
  }
  { int r = tid >> 4, s = tid & 15;
    float sv = ISQ ? mxs[r] : stab[bh];
    float dg = dgs[r];
    u16* dst = P + ((size_t)bh*n + row0 + r)*MFc;
    #pragma unroll
    for (int j=0;j<16;j++){
      int m = s*16+j;
      dst[m] = f2bf((__expf(xds[r][m] - dg - sv) + 1e-4f)*0.0625f);
    }
  }
}

// Causal attention, all-MFMA. P_Q,P_K: [bh][n][256] bf16; Vt: [bh][64][n] bf16.
__global__ __launch_bounds__(256) void k_causal_mfma(const u16* __restrict__ PQ,
    const u16* __restrict__ PK, const u16* __restrict__ Vt, u16* __restrict__ O, int n)
{
  int ntile = n >> 4;                       // 9 for n=144
  int it = blockIdx.x % ntile, bh = blockIdx.x / ntile;
  int b = bh >> 3, h = bh & 7;
  int row0 = it << 4;
  int tid = threadIdx.x, w = tid >> 6, lane = tid & 63;
  int l15 = lane & 15, lg = lane >> 4;
  __shared__ u16 qp[16][264];
  __shared__ float sf[16][168];
  __shared__ u16 sb[16][168];
  __shared__ u16 vt[64][168];
  __shared__ float dns[16];
  __shared__ float red[16][16];
  #pragma unroll
  for (int p=0;p<4;p++){
    int idx = tid + (p<<8);
    int r = idx >> 6, c4 = (idx & 63)*4;
    *(u16x4*)&qp[r][c4] = *(const u16x4*)(PQ + ((size_t)bh*n + row0 + r)*MFc + c4);
  }
  for (int i = tid; i < 64*40; i += 256){
    int r = i / 40, c4 = (i % 40)*4;
    u16x4 v = {0,0,0,0};
    if (c4 < 144) v = *(const u16x4*)(Vt + ((size_t)bh*64 + r)*(size_t)n + c4);
    *(u16x4*)&vt[r][c4] = v;
  }
  { int r = tid >> 4, c = 144 + (tid & 15);
    sb[r][c] = 0; sf[r][c] = 0.f; }
  __syncthreads();
  for (int jt = w; jt < 9; jt += 4){
    fx4 a2 = {0.f,0.f,0.f,0.f};
    #pragma unroll
    for (int ks=0; ks<8; ks++){
      bfx8 af = *(const bfx8*)&qp[l15][ks*32 + lg*8];
      bfx8 bf = *(const bfx8*)(PK + ((size_t)bh*n + jt*16 + l15)*MFc + ks*32 + lg*8);
      a2 = __builtin_amdgcn_mfma_f32_16x16x32_bf16(af, bf, a2, 0, 0, 0);
    }
    int jg = jt*16 + l15;
    #pragma unroll
    for (int r=0;r<4;r++){
      int il = lg*4 + r;
      float v = (jg <= row0 + il) ? a2[r] : 0.f;
      sf[il][jg] = v;
      sb[il][jg] = f2bf(v);
    }
  }
  __syncthreads();
  { int r = tid >> 4, s = tid & 15;
    float pd = 0;
    #pragma unroll
    for (int q=0;q<9;q++) pd += sf[r][s*9 + q];
    red[r][s] = pd; }
  __syncthreads();
  if (tid < 16){
    float s = 0;
    #pragma unroll
    for (int j=0;j<16;j++) s += red[tid][j];
    dns[tid] = 1.0f / (s + 1e-6f);
  }
  __syncthreads();
  fx4 a2 = {0.f,0.f,0.f,0.f};
  #pragma unroll
  for (int ks=0; ks<5; ks++){
    bfx8 af = *(const bfx8*)&sb[l15][ks*32 + lg*8];
    bfx8 bf = *(const bfx8*)&vt[w*16 + l15][ks*32 + lg*8];
    a2 = __builtin_amdgcn_mfma_f32_16x16x32_bf16(af, bf, a2, 0, 0, 0);
  }
  #pragma unroll
  for (int r=0;r<4;r++){
    int il = lg*4 + r;
    O[((size_t)b*n + row0 + il)*DMc + h*64 + w*16 + l15] = f2bf(a2[r]*dns[il]);
  }
}

// LayerNorm over rows of 512, templated on input/residual/output bf16-ness.
template<int ABF, int RBF, int OBF>
__global__ __launch_bounds__(128) void k_ln(const void* __restrict__ Ap, const void* __restrict__ Rp,
    const float* __restrict__ g, const float* __restrict__ beta, void* __restrict__ outp)
{
  size_t row = blockIdx.x; int t = threadIdx.x;
  float4 v;
  if (ABF){
    u16x4 a = *((const u16x4*)Ap + row*(DMc/4) + t);
    v.x = bf2f(a.x); v.y = bf2f(a.y); v.z = bf2f(a.z); v.w = bf2f(a.w);
  } else {
    v = *((const float4*)Ap + row*(DMc/4) + t);
  }
  if (Rp){
    if (RBF){
      u16x4 wv = *((const u16x4*)Rp + row*(DMc/4) + t);
      v.x += bf2f(wv.x); v.y += bf2f(wv.y); v.z += bf2f(wv.z); v.w += bf2f(wv.w);
    } else {
      float4 wv = *((const float4*)Rp + row*(DMc/4) + t);
      v.x += wv.x; v.y += wv.y; v.z += wv.z; v.w += wv.w;
    }
  }
  __shared__ float red[2];
  float s = v.x+v.y+v.z+v.w;
  for (int o=32;o;o>>=1) s += __shfl_xor(s,o);
  if ((t&63)==0) red[t>>6]=s;
  __syncthreads();
  float mu = (red[0]+red[1]) * (1.0f/DMc);
  float dx=v.x-mu, dy=v.y-mu, dz=v.z-mu, dw=v.w-mu;
  float qq = dx*dx+dy*dy+dz*dz+dw*dw;
  __syncthreads();
  for (int o=32;o;o>>=1) qq += __shfl_xor(qq,o);
  if ((t&63)==0) red[t>>6]=qq;
  __syncthreads();
  float var = (red[0]+red[1]) * (1.0f/DMc);
  float rs = 1.0f / sqrtf(var + 1e-5f);
  const float4 g4 = *(const float4*)(g + t*4);
  const float4 b4 = *(const float4*)(beta + t*4);
  float ox = dx*rs*g4.x + b4.x;
  float oy = dy*rs*g4.y + b4.y;
  float oz = dz*rs*g4.z + b4.z;
  float ow = dw*rs*g4.w + b4.w;
  if (OBF){
    u16x4 o4; o4.x=f2bf(ox); o4.y=f2bf(oy); o4.z=f2bf(oz); o4.w=f2bf(ow);
    *((u16x4*)outp + row*(DMc/4) + t) = o4;
  } else {
    float4 o4; o4.x=ox; o4.y=oy; o4.z=oz; o4.w=ow;
    *((float4*)outp + row*(DMc/4) + t) = o4;
  }
}

// final projection + de-standardize + slice last 96
__global__ __launch_bounds__(64) void k_final(const float* __restrict__ X, const float* __restrict__ pw,
   const float* __restrict__ pb, const float* __restrict__ means, const float* __restrict__ stdev,
   float* __restrict__ outp)
{
  int blk = blockIdx.x; int lo = blk % PREDc; int b = blk / PREDc;
  int l = lo + (LDc - PREDc);
  int t = threadIdx.x;
  float acc[7];
  #pragma unroll
  for (int c=0;c<7;c++) acc[c]=0;
  const float* xr = X + ((size_t)b*LDc + l)*DMc;
  for (int d=t; d<DMc; d+=64){
    float xv = xr[d];
    #pragma unroll
    for (int c=0;c<7;c++) acc[c] = fmaf(xv, pw[d*7+c], acc[c]);
  }
  #pragma unroll
  for (int c=0;c<7;c++){
    float s = acc[c];
    for (int o=32;o;o>>=1) s += __shfl_xor(s,o);
    if (t==0)
      outp[((size_t)b*PREDc + lo)*7 + c] = (s + pb[c]) * stdev[b*7+c] + means[b*7+c];
  }
}

// =====================================================================
extern "C" void kernel_launch(void* const* d_in, const int* in_sizes, int n_in,
                              void* d_out, int out_size, void* d_ws, size_t ws_size,
                              hipStream_t stream)
{
  (void)in_sizes; (void)n_in;
  const float* x_enc        = (const float*)d_in[0];
  const float* x_mark_enc   = (const float*)d_in[1];
  const float* x_dec        = (const float*)d_in[2];
  const float* x_mark_dec   = (const float*)d_in[3];
  const float* emb_conv_enc = (const float*)d_in[4];
  const float* emb_time_enc = (const float*)d_in[5];
  const float* emb_conv_dec = (const float*)d_in[6];
  const float* emb_time_dec = (const float*)d_in[7];
  const float* enc_Wq = (const float*)d_in[8];
  const float* enc_Wk = (const float*)d_in[9];
  const float* enc_Wv = (const float*)d_in[10];
  const float* enc_Wo = (const float*)d_in[11];
  const float* enc_bo = (const float*)d_in[12];
  const float* enc_ff1 = (const float*)d_in[13];
  const float* enc_b1  = (const float*)d_in[14];
  const float* enc_ff2 = (const float*)d_in[15];
  const float* enc_b2  = (const float*)d_in[16];
  const float* enc_ln_g = (const float*)d_in[17];
  const float* enc_ln_b = (const float*)d_in[18];
  const float* enc_fg = (const float*)d_in[19];
  const float* enc_fb = (const float*)d_in[20];
  const float* dec_sWq = (const float*)d_in[21];
  const float* dec_sWk = (const float*)d_in[22];
  const float* dec_sWv = (const float*)d_in[23];
  const float* dec_sWo = (const float*)d_in[24];
  const float* dec_sbo = (const float*)d_in[25];
  const float* dec_cWq = (const float*)d_in[26];
  const float* dec_cWk = (const float*)d_in[27];
  const float* dec_cWv = (const float*)d_in[28];
  const float* dec_cWo = (const float*)d_in[29];
  const float* dec_cbo = (const float*)d_in[30];
  const float* dec_ff1 = (const float*)d_in[31];
  const float* dec_b1  = (const float*)d_in[32];
  const float* dec_ff2 = (const float*)d_in[33];
  const float* dec_b2  = (const float*)d_in[34];
  const float* dec_ln_g = (const float*)d_in[35];
  const float* dec_ln_b = (const float*)d_in[36];
  const float* dec_fg = (const float*)d_in[37];
  const float* dec_fb = (const float*)d_in[38];
  const float* proj_w = (const float*)d_in[39];
  const float* proj_b = (const float*)d_in[40];
  float* outp = (float*)d_out;
  float* W = (float*)d_ws;

  // ---- workspace carve (float units). Total ~= 123 MB ----
  size_t o = 0;
  #define ALLOCF(nm, n) size_t nm = o; o += (((size_t)(n)) + 63) & ~(size_t)63;
  ALLOCF(o_proj, 4*MFc*DHc)
  ALLOCF(o_projbf, 2*MFc*DHc)            // 4 sets of bf16 proj (u16)
  ALLOCF(o_means, BB*7)
  ALLOCF(o_std,   BB*7)
  ALLOCF(o_rmE, (size_t)BHc*LEc)
  ALLOCF(o_rmD, (size_t)BHc*LDc)
  ALLOCF(o_stab, BHc)
  ALLOCF(o_KS, KSn)
  ALLOCF(o_PE, (size_t)LEc*DMc)          // sinusoidal PE table (dec = rows 0..143)
  ALLOCF(o_Dx1, (size_t)NDc*DMc)         // decoder x1 (bf16 in first half; survives cross)
  ALLOCF(o_WT, 5242880)                  // 10,485,760 bf16 weights
  ALLOCF(o_Xb, (size_t)NEc*DMc)          // residual stream f32
  ALLOCF(o_X1, (size_t)NEc*DMc)          // x1bf + attnbf (u16 halves) / Vt+KVT / dec f32 slots
  ALLOCF(o_U,  11796480)                 // 23,592,960 u16 union region
  #undef ALLOCF
  size_t needed_bytes = o * sizeof(float);
  if (ws_size < needed_bytes){
    k_zero<<<(out_size+255)/256, 256, 0, stream>>>(outp, out_size);
    return;
  }

  float* Xb  = W + o_Xb;
  float* X1  = W + o_X1;
  float* KS  = W + o_KS;
  float* PE  = W + o_PE;
  float* rmE = W + o_rmE;
  float* rmD = W + o_rmD;
  float* stb = W + o_stab;
  u16*  WTb = (u16*)(W + o_WT);
  u16*  Uh  = (u16*)(W + o_U);
  u16*  PJB = (u16*)(W + o_projbf);

  const size_t NEu = (size_t)NEc*DMc;      // 5,898,240
  const size_t NDu = (size_t)NDc*DMc;      // 1,179,648
  // encoder bf16 slots
  u16* Tq = Uh;            u16* Tk = Uh + NEu;
  u16* Tv = Uh + 2*NEu;    u16* Oe = Uh + 3*NEu;
  u16* FFb = Uh;                                   // full-M FF intermediate (aliases all slots)
  // Vt (full 128 bh) + KVT live in X1 during kv/attn phases
  u16*   VtU  = (u16*)X1;                          // 5,898,240 u16
  u16*   KVTu = (u16*)(X1 + 2949120);              // 2,097,152 u16
  // encoder bf16 x1/attn slots (X1 region as u16 halves)
  u16*   x1bf   = (u16*)X1;                        // [0, NEu)
  u16*   attnbf = (u16*)X1 + NEu;                  // [NEu, 2*NEu)
  // decoder phase aliases (in U)
  u16* dTq = Uh;           u16* dTk = Uh + NDu;
  u16* dTv = Uh + 2*NDu;   u16* dOd = Uh + 3*NDu;
  u16* PQb = Uh + 4*NDu;                            // [128][144][256] bf16
  u16* PKb = PQb + (size_t)BHc*LDc*MFc;             // + 4,718,592
  u16* VtD = PKb + (size_t)BHc*LDc*MFc;             // [128][64][144] bf16
  // cross phase aliases
  u16* cTk = Uh;           u16* cTv = Uh + NEu;
  u16* dTq2 = Uh + 2*NEu;  u16* cOd = Uh + 2*NEu + NDu;
  u16* dFF = Uh;                                   // 2304x2048
  // decoder f32 slots in X1 (dead during kv phases)
  float* DX  = X1 + 0*NDu;
  float* Da  = X1 + 1*NDu;
  float* Dx2 = X1 + 2*NDu;
  float* Dy  = X1 + 3*NDu;
  u16* dAttnbf = (u16*)Da;                         // bf16 self-attn out (first half of Da slot)
  u16* Dx1bf   = (u16*)(W + o_Dx1);                // bf16 x1 (own carve, survives cross)
  u16* Dx2bf   = (u16*)Dx2;                        // bf16 x2 (first half of Dx2 slot)

  // ---- host: exact numpy ORF projection matrices, upload ----
  static float h_proj[4*MFc*DHc];
  build_all_proj(h_proj);
  hipMemcpyAsync(W + o_proj, h_proj, sizeof(h_proj), hipMemcpyHostToDevice, stream);
  k_projbf<<<(4*MFc*DHc)/256, 256, 0, stream>>>(W + o_proj, PJB, 4*MFc*DHc);
  const u16* pb_enc0  = PJB + 0*MFc*DHc;
  const u16* pb_enc1  = PJB + 1*MFc*DHc;
  const u16* pb_self  = PJB + 2*MFc*DHc;
  const u16* pb_cross = PJB + 3*MFc*DHc;

  // ---- PE table ----
  k_petab<<<(LEc*DMc)/256, 256, 0, stream>>>(PE);

  // ---- device: transpose+cast all GEMM weights to bf16 WT[N][K] ----
  size_t wto = 0;
  auto xpose = [&](const float* Wsrc, int K, int N) -> const u16* {
    u16* dst = WTb + wto; wto += (size_t)K*N;
    k_wtr<<<dim3(K/32, N/32), 256, 0, stream>>>(Wsrc, dst, K, N);
    return dst;
  };
  const u16 *wQ[2], *wK[2], *wV[2], *wO[2], *wF1[2], *wF2[2];
  for (int i=0;i<2;i++){
    wQ[i]  = xpose(enc_Wq + (size_t)i*DMc*DMc, DMc, DMc);   // wQ,wK,wV contiguous
    wK[i]  = xpose(enc_Wk + (size_t)i*DMc*DMc, DMc, DMc);
    wV[i]  = xpose(enc_Wv + (size_t)i*DMc*DMc, DMc, DMc);
    wO[i]  = xpose(enc_Wo + (size_t)i*DMc*DMc, DMc, DMc);
    wF1[i] = xpose(enc_ff1 + (size_t)i*DMc*FFc, DMc, FFc);
    wF2[i] = xpose(enc_ff2 + (size_t)i*FFc*DMc, FFc, DMc);
  }
  const u16* wsQ = xpose(dec_sWq, DMc, DMc);   // wsQ,wsK,wsV contiguous
  const u16* wsK = xpose(dec_sWk, DMc, DMc);
  const u16* wsV = xpose(dec_sWv, DMc, DMc);
  const u16* wsO = xpose(dec_sWo, DMc, DMc);
  const u16* wcQ = xpose(dec_cWq, DMc, DMc);
  const u16* wcK = xpose(dec_cWk, DMc, DMc);   // wcK,wcV contiguous
  const u16* wcV = xpose(dec_cWv, DMc, DMc);
  const u16* wcO = xpose(dec_cWo, DMc, DMc);
  const u16* wdF1 = xpose(dec_ff1, DMc, FFc);
  const u16* wdF2 = xpose(dec_ff2, FFc, DMc);
  (void)wK; (void)wV; (void)wsK; (void)wsV; (void)wcV;

  // non-causal K-side chain: rowmax(MFMA) -> stab -> Vt -> m-split MFMA kv
  auto kv_chain = [&](const u16* Kbuf, const u16* Vbuf, const u16* pjb){
    k_rowmax_mfma<<<BHc*(LEc/16), 256, 0, stream>>>(Kbuf, pjb, rmE, LEc);
    k_stab<<<BHc, 256, 0, stream>>>(rmE, stb, LEc);
    k_vtr<<<BHc*(LEc/16), 256, 0, stream>>>(Vbuf, VtU, LEc);
    k_kvfull<<<BHc*2*2, 256, 0, stream>>>(Kbuf, VtU, pjb, stb, KVTu, KS, LEc);
  };

  // ---- RevIN stats + encoder embed ----
  k_meanstd<<<BB*7, 64, 0, stream>>>(x_enc, W+o_means, W+o_std);
  k_embed<<<(BB*LEc*DMc)/256, 256, 0, stream>>>(x_enc, x_mark_enc, emb_conv_enc, emb_time_enc,
                                                PE, W+o_means, W+o_std, LEc, 1, Xb);

  // ---- encoder layers ----
  for (int i=0;i<2;i++){
    const float* bo = enc_bo + (size_t)i*DMc;
    const float* b1 = enc_b1  + (size_t)i*FFc;
    const float* b2 = enc_b2  + (size_t)i*DMc;
    const float* g0 = enc_ln_g + (size_t)(i*2+0)*DMc;
    const float* e0 = enc_ln_b + (size_t)(i*2+0)*DMc;
    const float* g1 = enc_ln_g + (size_t)(i*2+1)*DMc;
    const float* e1 = enc_ln_b + (size_t)(i*2+1)*DMc;
    const u16*   pjb = (i==0) ? pb_enc0 : pb_enc1;

    k_gemm_qkv<3><<<dim3((1536/128)*(NEc/128)), 256, 0, stream>>>(Xb, wQ[i], Tq, Tk, Tv, NEc, DMc);
    kv_chain(Tk, Tv, pjb);
    k_attn_mfma<<<BHc*(LEc/16), 256, 0, stream>>>(Tq, pjb, KVTu, KS, Oe, LEc);
    gemm_bf(Oe, wO[i], bo, attnbf, NEc, DMc, DMc, 1,1,0, stream);        // attn out bf16
    k_ln<1,0,1><<<NEc, 128, 0, stream>>>(attnbf, Xb, g0, e0, x1bf);      // x1 -> bf16
    gemm_bf(x1bf, wF1[i], b1, FFb, NEc, FFc, DMc, 1,1,1, stream);        // gelu -> bf16
    gemm_bf(FFb, wF2[i], b2, Xb, NEc, DMc, FFc, 1,0,0, stream);          // y -> Xb f32
    k_ln<0,1,0><<<NEc, 128, 0, stream>>>(Xb, x1bf, g1, e1, Xb);          // enc = LN(y+x1)
  }
  k_ln<0,0,0><<<NEc, 128, 0, stream>>>(Xb, nullptr, enc_fg, enc_fb, Xb); // final enc norm

  // ---- decoder ----
  k_embed<<<(BB*LDc*DMc)/256, 256, 0, stream>>>(x_dec, x_mark_dec, emb_conv_dec, emb_time_dec,
                                                PE, W+o_means, W+o_std, LDc, 0, DX);
  // self (causal), all-MFMA
  k_gemm_qkv<3><<<dim3((1536/128)*(NDc/128)), 256, 0, stream>>>(DX, wsQ, dTq, dTk, dTv, NDc, DMc);
  k_rowmax_mfma<<<BHc*(LDc/16), 256, 0, stream>>>(dTk, pb_self, rmD, LDc);
  k_stab<<<BHc, 256, 0, stream>>>(rmD, stb, LDc);
  k_fmap_mfma<1><<<BHc*(LDc/16), 256, 0, stream>>>(dTq, pb_self, nullptr, PQb, LDc);
  k_fmap_mfma<0><<<BHc*(LDc/16), 256, 0, stream>>>(dTk, pb_self, stb, PKb, LDc);
  k_vtr<<<BHc*(LDc/16), 256, 0, stream>>>(dTv, VtD, LDc);
  k_causal_mfma<<<BHc*(LDc/16), 256, 0, stream>>>(PQb, PKb, VtD, dOd, LDc);
  gemm_bf(dOd, wsO, dec_sbo, dAttnbf, NDc, DMc, DMc, 1,1,0, stream);
  k_ln<1,0,1><<<NDc, 128, 0, stream>>>(dAttnbf, DX, dec_ln_g + 0*DMc, dec_ln_b + 0*DMc, Dx1bf); // x1 bf16

  // cross
  gemm_bf(Dx1bf, wcQ, nullptr, dTq2, NDc, DMc, DMc, 1,1,0, stream);
  k_gemm_qkv<2><<<dim3((1024/128)*(NEc/128)), 256, 0, stream>>>(Xb, wcK, cTk, cTv, nullptr, NEc, DMc);
  kv_chain(cTk, cTv, pb_cross);
  k_attn_mfma<<<BHc*(LDc/16), 256, 0, stream>>>(dTq2, pb_cross, KVTu, KS, cOd, LDc);
  gemm_bf(cOd, wcO, dec_cbo, Da, NDc, DMc, DMc, 1,0,0, stream);
  k_ln<0,1,1><<<NDc, 128, 0, stream>>>(Da, Dx1bf, dec_ln_g + 1*DMc, dec_ln_b + 1*DMc, Dx2bf);  // x2 bf16

  // FF + final norms + projection
  gemm_bf(Dx2bf, wdF1, dec_b1, dFF, NDc, FFc, DMc, 1,1,1, stream);
  gemm_bf(dFF, wdF2, dec_b2, Dy, NDc, DMc, FFc, 1,0,0, stream);
  k_ln<0,1,0><<<NDc, 128, 0, stream>>>(Dy, Dx2bf, dec_ln_g + 2*DMc, dec_ln_b + 2*DMc, Da);
  k_ln<0,0,0><<<NDc, 128, 0, stream>>>(Da, nullptr, dec_fg, dec_fb, Da);
  k_final<<<BB*PREDc, 64, 0, stream>>>(Da, proj_w, proj_b, W+o_means, W+o_std, outp);
}

// Round 14
// 1343.209 us; speedup vs baseline: 2.7898x; 2.7898x over previous
//
#include <hip/hip_runtime.h>
#include <math.h>
#include <string.h>

// ---------------- model constants ----------------
#define BB    16
#define LEc   720
#define LDc   144
#define PREDc 96
#define DMc   512
#define NHc   8
#define DHc   64
#define MFc   256
#define FFc   2048
#define NEc   (BB*LEc)   // 11520
#define NDc   (BB*LDc)   // 2304
#define BHc   (BB*NHc)   // 128
#define KSn   ((size_t)BHc*MFc)       // 32,768

typedef unsigned int u32;
typedef unsigned short u16;
typedef unsigned long long u64;
typedef unsigned __int128 u128;

typedef short bfx8 __attribute__((ext_vector_type(8)));
typedef float fx4  __attribute__((ext_vector_type(4)));
typedef unsigned short u16x4 __attribute__((ext_vector_type(4)));

// =====================================================================
// Host-side exact replication of numpy default_rng(seed) -> PCG64 ->
// ziggurat standard_normal, plus LAPACK-convention Householder QR.
// =====================================================================
struct NpSeedSeq {
  u32 pool[4];
  u32 hc;
  u32 hashmix(u32 v){ v ^= hc; hc *= 0x931e8875u; v *= hc; v ^= v >> 16; return v; }
  static u32 mixv(u32 x, u32 y){ u32 r = x*0xca01f9ddu - y*0x4973f715u; r ^= r >> 16; return r; }
  NpSeedSeq(u32 entropy){
    hc = 0x43b0d7e5u;
    for (int i=0;i<4;i++) pool[i] = hashmix(i==0 ? entropy : 0u);
    for (int s=0;s<4;s++)
      for (int d=0;d<4;d++)
        if (s!=d) pool[d] = mixv(pool[d], hashmix(pool[s]));
  }
  void generate8(u32* w){
    u32 h = 0x8b51f9ddu;
    for (int i=0;i<8;i++){
      u32 v = pool[i & 3];
      v ^= h; h *= 0x58f38dedu; v *= h; v ^= v >> 16;
      w[i] = v;
    }
  }
};

struct NpPCG64 {
  u128 state, inc;
  static u128 pcgmult(){ return ((u128)0x2360ed051fc65da4ull << 64) | 0x4385df649fccf645ull; }
  void step(){ state = state * pcgmult() + inc; }
  NpPCG64(u32 seed){
    NpSeedSeq ss(seed);
    u32 w[8]; ss.generate8(w);
    u64 v0 = (u64)w[0] | ((u64)w[1] << 32);
    u64 v1 = (u64)w[2] | ((u64)w[3] << 32);
    u64 v2 = (u64)w[4] | ((u64)w[5] << 32);
    u64 v3 = (u64)w[6] | ((u64)w[7] << 32);
    u128 initstate = ((u128)v0 << 64) | v1;
    u128 initseq   = ((u128)v2 << 64) | v3;
    state = 0; inc = (initseq << 1) | 1;
    step(); state += initstate; step();
  }
  u64 next64(){
    step();
    u64 hi = (u64)(state >> 64), lo = (u64)state;
    u32 rot = (u32)(state >> 122);
    u64 x = hi ^ lo;
    return (x >> rot) | (x << ((64u - rot) & 63u));
  }
  double nextDouble(){ return (double)(next64() >> 11) * (1.0/9007199254740992.0); }
};

static u64    zki[256];
static double zwi[256], zfi[256];
static void init_zig(){
  const double r  = 3.6541528853610087963519472518;
  const double mq = 4503599627370496.0; // 2^52
  double fr = exp(-0.5*r*r);
  double vv = r*fr + sqrt(M_PI*0.5)*erfc(r/sqrt(2.0));
  double q  = vv/fr;
  zki[0] = (u64)((r/q)*mq);
  zki[1] = 0;
  zwi[0] = q/mq; zwi[255] = r/mq;
  zfi[0] = 1.0;  zfi[255] = fr;
  double tn = r, dn = r;
  for (int i=254;i>=1;i--){
    dn = sqrt(-2.0*log(vv/dn + exp(-0.5*dn*dn)));
    zki[i+1] = (u64)((dn/tn)*mq);
    tn = dn;
    zfi[i] = exp(-0.5*dn*dn);
    zwi[i] = dn/mq;
  }
}

static double std_normal(NpPCG64& g){
  const double nor_r = 3.6541528853610087963519472518;
  const double inv_r = 0.27366123732975827203338247596;
  for(;;){
    u64 rr = g.next64();
    int idx  = (int)(rr & 0xff); rr >>= 8;
    int sign = (int)(rr & 1);
    u64 rabs = (rr >> 1) & 0x000fffffffffffffULL;
    double x = (double)rabs * zwi[idx];
    if (sign) x = -x;
    if (rabs < zki[idx]) return x;
    if (idx == 0){
      double xx, yy;
      do {
        xx = -inv_r * log1p(-g.nextDouble());
        yy = -log1p(-g.nextDouble());
      } while (yy + yy <= xx*xx);
      return ((rabs >> 8) & 1) ? -(nor_r + xx) : (nor_r + xx);
    } else {
      if ((zfi[idx-1]-zfi[idx]) * g.nextDouble() + zfi[idx] < exp(-0.5*x*x)) return x;
    }
  }
}

// Householder QR (LAPACK dgeqrf/dorgqr convention), A,Q row-major 64x64.
static void qr_q64(double* A, double* Q){
  const int n = 64;
  static double V[64][64];
  static double tau[64];
  for (int j=0;j<n;j++){
    double alpha = A[j*n+j];
    double xn2 = 0;
    for (int i=j+1;i<n;i++) xn2 += A[i*n+j]*A[i*n+j];
    double xnorm = sqrt(xn2);
    if (xnorm == 0.0){
      tau[j] = 0.0;
      for (int i=j;i<n;i++) V[j][i] = (i==j) ? 1.0 : 0.0;
      continue;
    }
    double beta = -copysign(hypot(alpha, xnorm), alpha);
    double tj = (beta - alpha)/beta;
    double sc = 1.0/(alpha - beta);
    tau[j] = tj;
    V[j][j] = 1.0;
    for (int i=j+1;i<n;i++) V[j][i] = A[i*n+j]*sc;
    A[j*n+j] = beta;
    for (int c=j+1;c<n;c++){
      double w = 0;
      for (int i=j;i<n;i++) w += V[j][i]*A[i*n+c];
      w *= tj;
      for (int i=j;i<n;i++) A[i*n+c] -= V[j][i]*w;
    }
  }
  for (int i=0;i<n;i++) for (int c=0;c<n;c++) Q[i*n+c] = (i==c)?1.0:0.0;
  for (int j=n-1;j>=0;j--){
    double tj = tau[j];
    if (tj == 0.0) continue;
    for (int c=0;c<n;c++){
      double w = 0;
      for (int i=j;i<n;i++) w += V[j][i]*Q[i*n+c];
      w *= tj;
      for (int i=j;i<n;i++) Q[i*n+c] -= V[j][i]*w;
    }
  }
}

static void build_orf(u32 seed, float* outp){ // outp: [256*64]
  NpPCG64 g(seed);
  static double mat[MFc][DHc];
  static double A[64*64], Q[64*64];
  for (int blk=0; blk<4; blk++){
    for (int i=0;i<4096;i++) A[i] = std_normal(g);
    qr_q64(A, Q);
    for (int r=0;r<64;r++)
      for (int c=0;c<64;c++)
        mat[blk*64 + r][c] = Q[c*64 + r];   // block.T
  }
  for (int r=0;r<MFc;r++){
    double ss = 0;
    double row[64];
    for (int c=0;c<64;c++){ row[c] = std_normal(g); ss += row[c]*row[c]; }
    double nrm = sqrt(ss);
    for (int c=0;c<64;c++) outp[r*64 + c] = (float)(nrm * mat[r][c]);
  }
}

static void build_all_proj(float* h){
  init_zig();
  const u32 seeds[4] = {0u, 1u, 10u, 11u};
  for (int s=0;s<4;s++) build_orf(seeds[s], h + (size_t)s*MFc*DHc);
}

// =====================================================================
// Device helpers
// =====================================================================
__device__ __forceinline__ u16 f2bf(float x){
  u32 u = __builtin_bit_cast(u32, x);
  u32 r = (u + 0x7FFFu + ((u >> 16) & 1u)) >> 16;
  return (u16)r;
}
__device__ __forceinline__ float bf2f(u16 x){
  return __builtin_bit_cast(float, ((u32)x) << 16);
}

// =====================================================================
// Device kernels
// =====================================================================

__global__ __launch_bounds__(256) void k_zero(float* __restrict__ p, int n){
  int i = blockIdx.x*256 + threadIdx.x;
  if (i < n) p[i] = 0.f;
}

__global__ __launch_bounds__(256) void k_projbf(const float* __restrict__ p, u16* __restrict__ pb, int n){
  int i = blockIdx.x*256 + threadIdx.x;
  if (i < n) pb[i] = f2bf(p[i]);
}

// sinusoidal PE table [720][512] (decoder uses rows 0..143, same formula)
__global__ __launch_bounds__(256) void k_petab(float* __restrict__ pe){
  int idx = blockIdx.x*256 + threadIdx.x;      // 720*512
  int d = idx & 511; int l = idx >> 9;
  int i2 = d & ~1;
  float div = expf((float)i2 * (-0.017988946039015984f)); // -ln(10000)/512
  float ang = (float)l * div;
  pe[idx] = (d & 1) ? cosf(ang) : sinf(ang);
}

// weight transpose + cast: WT[n][k] = bf16(W[k][n])
__global__ __launch_bounds__(256) void k_wtr(const float* __restrict__ W, u16* __restrict__ WT,
                                             int K, int N){
  __shared__ float t[32][33];
  int kb = blockIdx.x*32, nb = blockIdx.y*32;
  int tx = threadIdx.x & 31, ty = threadIdx.x >> 5;
  #pragma unroll
  for (int p=0;p<4;p++)
    t[ty + p*8][tx] = W[(size_t)(kb + ty + p*8)*N + nb + tx];
  __syncthreads();
  #pragma unroll
  for (int p=0;p<4;p++)
    WT[(size_t)(nb + ty + p*8)*K + kb + tx] = f2bf(t[tx][ty + p*8]);
}

// RevIN stats: one block per (b,c)
__global__ __launch_bounds__(64) void k_meanstd(const float* __restrict__ x,
                                                float* __restrict__ means, float* __restrict__ stdev){
  int bc = blockIdx.x; int b = bc/7, c = bc%7;
  int t = threadIdx.x;
  float s=0;
  for (int l=t; l<LEc; l+=64) s += x[((size_t)b*LEc+l)*7 + c];
  for (int o=32;o;o>>=1) s += __shfl_down(s,o);
  s = __shfl(s,0);
  float mu = s / (float)LEc;
  float v=0;
  for (int l=t; l<LEc; l+=64){ float d = x[((size_t)b*LEc+l)*7+c]-mu; v += d*d; }
  for (int o=32;o;o>>=1) v += __shfl_down(v,o);
  if (t==0){ means[bc]=mu; stdev[bc]=sqrtf(v/(float)LEc + 1e-5f); }
}

// token embed: circular conv(k=3) + PE table + timeF linear
__global__ __launch_bounds__(256) void k_embed(const float* __restrict__ x, const float* __restrict__ mark,
    const float* __restrict__ convw, const float* __restrict__ timew, const float* __restrict__ pe,
    const float* __restrict__ means, const float* __restrict__ stdev,
    int L, int donorm, float* __restrict__ outp)
{
  size_t idx = (size_t)blockIdx.x*256 + threadIdx.x;
  size_t total = (size_t)BB*L*DMc;
  if (idx >= total) return;
  int d = (int)(idx % DMc); size_t bl = idx / DMc; int l = (int)(bl % L); int b = (int)(bl / L);
  int lm = (l==0)? L-1 : l-1;
  int lp = (l==L-1)? 0 : l+1;
  float acc = pe[(size_t)l*DMc + d];
  const float* xb = x + (size_t)b*L*7;
  #pragma unroll
  for (int c=0;c<7;c++){
    float v0 = xb[(size_t)lm*7+c], v1 = xb[(size_t)l*7+c], v2 = xb[(size_t)lp*7+c];
    if (donorm){
      float mu = means[b*7+c], sd = stdev[b*7+c];
      v0=(v0-mu)/sd; v1=(v1-mu)/sd; v2=(v2-mu)/sd;
    }
    acc += v0*convw[(0*7+c)*DMc+d] + v1*convw[(1*7+c)*DMc+d] + v2*convw[(2*7+c)*DMc+d];
  }
  const float* mb = mark + ((size_t)b*L + l)*4;
  #pragma unroll
  for (int t=0;t<4;t++) acc += mb[t]*timew[t*DMc+d];
  outp[idx] = acc;
}

// ------------------ bf16 MFMA GEMM (XCD-swizzled) ------------------
template<int A_BF16, int OUT_BF16, int GELU>
__global__ __launch_bounds__(256) void k_gemm_mfma(
    const void* __restrict__ Ap, const u16* __restrict__ WT,
    const float* __restrict__ bias, void* __restrict__ Cp,
    int M, int N, int K)
{
  __shared__ u16 As[128][40];  // [row][k], +8 pad
  __shared__ u16 Bs[128][40];  // [col][k], +8 pad
  int nb = N >> 7;
  int bid = blockIdx.x;
  int nwg = gridDim.x;
  if (!(nwg & 7)) bid = ((bid & 7) * (nwg >> 3)) + (bid >> 3);   // XCD-contiguous row-bands
  int bx = bid % nb, by = bid / nb;
  int row0 = by << 7, col0 = bx << 7;
  int tid = threadIdx.x;
  int wid = tid >> 6, lane = tid & 63;
  int wr = (wid >> 1) * 64, wc = (wid & 1) * 64;
  int l15 = lane & 15, lg = lane >> 4;
  fx4 acc[4][4];
  #pragma unroll
  for (int i=0;i<4;i++)
    #pragma unroll
    for (int j=0;j<4;j++)
      #pragma unroll
      for (int r=0;r<4;r++) acc[i][j][r] = 0.f;

  for (int k0 = 0; k0 < K; k0 += 32){
    if (A_BF16){
      const u16* A = (const u16*)Ap;
      #pragma unroll
      for (int p=0;p<2;p++){
        int idx = tid + (p<<8);
        int r = idx >> 2, kq = (idx & 3) << 3;
        *(bfx8*)&As[r][kq] = *(const bfx8*)(A + (size_t)(row0+r)*K + k0 + kq);
      }
    } else {
      const float* A = (const float*)Ap;
      #pragma unroll
      for (int p=0;p<4;p++){
        int idx = tid + (p<<8);
        int r = idx >> 3, kq = (idx & 7) << 2;
        float4 v = *(const float4*)(A + (size_t)(row0+r)*K + k0 + kq);
        u32 lo = (u32)f2bf(v.x) | ((u32)f2bf(v.y) << 16);
        u32 hi = (u32)f2bf(v.z) | ((u32)f2bf(v.w) << 16);
        *(u32*)&As[r][kq]   = lo;
        *(u32*)&As[r][kq+2] = hi;
      }
    }
    #pragma unroll
    for (int p=0;p<2;p++){
      int idx = tid + (p<<8);
      int c = idx >> 2, kq = (idx & 3) << 3;
      *(bfx8*)&Bs[c][kq] = *(const bfx8*)(WT + (size_t)(col0+c)*K + k0 + kq);
    }
    __syncthreads();
    int kg = lg << 3;
    bfx8 af[4], bf[4];
    #pragma unroll
    for (int i=0;i<4;i++) af[i] = *(const bfx8*)&As[wr + i*16 + l15][kg];
    #pragma unroll
    for (int j=0;j<4;j++) bf[j] = *(const bfx8*)&Bs[wc + j*16 + l15][kg];
    #pragma unroll
    for (int i=0;i<4;i++)
      #pragma unroll
      for (int j=0;j<4;j++)
        acc[i][j] = __builtin_amdgcn_mfma_f32_16x16x32_bf16(af[i], bf[j], acc[i][j], 0, 0, 0);
    __syncthreads();
  }
  #pragma unroll
  for (int j=0;j<4;j++){
    int col = col0 + wc + j*16 + l15;
    float bv = bias ? bias[col] : 0.f;
    #pragma unroll
    for (int i=0;i<4;i++){
      #pragma unroll
      for (int r=0;r<4;r++){
        int row = row0 + wr + i*16 + (lg<<2) + r;
        float v = acc[i][j][r] + bv;
        if (GELU) v = 0.5f*v*(1.0f + erff(v*0.7071067811865475f));
        if (OUT_BF16) ((u16*)Cp)[(size_t)row*N + col] = f2bf(v);
        else          ((float*)Cp)[(size_t)row*N + col] = v;
      }
    }
  }
}

static inline void gemm_bf(const void* A, const u16* WT, const float* bias, void* C,
                           int M, int N, int K, int abf, int obf, int gelu, hipStream_t st){
  dim3 g((N/128)*(M/128));
  if (abf && obf && gelu)  k_gemm_mfma<1,1,1><<<g,256,0,st>>>(A,WT,bias,C,M,N,K);
  else if (abf && obf)     k_gemm_mfma<1,1,0><<<g,256,0,st>>>(A,WT,bias,C,M,N,K);
  else if (abf)            k_gemm_mfma<1,0,0><<<g,256,0,st>>>(A,WT,bias,C,M,N,K);
  else if (gelu)           k_gemm_mfma<0,1,1><<<g,256,0,st>>>(A,WT,bias,C,M,N,K);
  else if (obf)            k_gemm_mfma<0,1,0><<<g,256,0,st>>>(A,WT,bias,C,M,N,K);
  else                     k_gemm_mfma<0,0,0><<<g,256,0,st>>>(A,WT,bias,C,M,N,K);
}

// per-row max_m of xd, MFMA version. out rowmax[bh][n] scaled by 64^-0.25.
__global__ __launch_bounds__(256) void k_rowmax_mfma(const u16* __restrict__ Kb,
    const u16* __restrict__ projbf, float* __restrict__ rowmax, int n)
{
  int ntile = n >> 4;
  int rt = blockIdx.x % ntile, bh = blockIdx.x / ntile;
  int b = bh >> 3, h = bh & 7;
  int row0 = rt << 4;
  int tid = threadIdx.x, w = tid >> 6, lane = tid & 63;
  int l15 = lane & 15, lg = lane >> 4;
  __shared__ u16 qs[16][72];
  __shared__ float xds[16][264];
  __shared__ float red[16][16];
  for (int i = tid; i < 16*16; i += 256){
    int r = i >> 4, dq = (i & 15)*4;
    *(u16x4*)&qs[r][dq] = *(const u16x4*)(Kb + ((size_t)b*n + row0 + r)*DMc + h*64 + dq);
  }
  __syncthreads();
  #pragma unroll
  for (int mt=0; mt<4; mt++){
    int m16 = (w*4+mt)*16;
    fx4 a2 = {0.f,0.f,0.f,0.f};
    #pragma unroll
    for (int ks=0; ks<2; ks++){
      bfx8 af = *(const bfx8*)&qs[l15][ks*32 + lg*8];
      bfx8 bf = *(const bfx8*)(projbf + (size_t)(m16+l15)*64 + ks*32 + lg*8);
      a2 = __builtin_amdgcn_mfma_f32_16x16x32_bf16(af, bf, a2, 0, 0, 0);
    }
    #pragma unroll
    for (int r=0;r<4;r++)
      xds[lg*4+r][m16+l15] = a2[r];
  }
  __syncthreads();
  { int r = tid >> 4, s = tid & 15;
    float mx = -1e30f;
    #pragma unroll
    for (int j=0;j<16;j++) mx = fmaxf(mx, xds[r][s*16+j]);
    red[r][s] = mx; }
  __syncthreads();
  if (tid < 16){
    float mx = -1e30f;
    #pragma unroll
    for (int j=0;j<16;j++) mx = fmaxf(mx, red[tid][j]);
    rowmax[(size_t)bh*n + row0 + tid] = mx * 0.35355339059327373f;
  }
}

__global__ __launch_bounds__(256) void k_stab(const float* __restrict__ rowmax, float* __restrict__ stab, int n){
  int bh = blockIdx.x; int tid = threadIdx.x;
  float mx = -1e30f;
  for (int i=tid;i<n;i+=256) mx = fmaxf(mx, rowmax[(size_t)bh*n+i]);
  __shared__ float red[4];
  for (int o=32;o;o>>=1) mx = fmaxf(mx, __shfl_xor(mx,o));
  if ((tid&63)==0) red[tid>>6]=mx;
  __syncthreads();
  if (tid==0) stab[bh] = fmaxf(fmaxf(red[0],red[1]),fmaxf(red[2],red[3]));
}

// V transpose per head: Vt[bh][d][n] bf16 from Vb[b*n][512]
__global__ __launch_bounds__(256) void k_vtr(const u16* __restrict__ Vb, u16* __restrict__ Vt, int n){
  int nt = n >> 4;
  int blk = blockIdx.x; int t16 = blk % nt; int bh = blk / nt;
  int b = bh >> 3, h = bh & 7;
  int n0 = t16 << 4;
  int t = threadIdx.x;
  __shared__ u16 vt[16][72];
  { int r = t >> 4, d0 = (t & 15) * 4;
    *(u16x4*)&vt[r][d0] = *(const u16x4*)(Vb + ((size_t)b*n + n0 + r)*DMc + h*64 + d0); }
  __syncthreads();
  { int d = t >> 2, j = t & 3;
    u16x4 o;
    o.x = vt[j*4+0][d]; o.y = vt[j*4+1][d]; o.z = vt[j*4+2][d]; o.w = vt[j*4+3][d];
    *(u16x4*)(Vt + ((size_t)bh*64 + d)*(size_t)n + n0 + j*4) = o; }
}

// Fused K feature-map + KV accumulation + KS, all-MFMA.
// grid = BHc*2 (bh x d-half). out: KVT[bh][64 d][256 m] bf16, KS[bh][256].
__global__ __launch_bounds__(256) void k_kvfull(const u16* __restrict__ Kb,
    const u16* __restrict__ Vt, const u16* __restrict__ projbf, const float* __restrict__ stab,
    u16* __restrict__ KVT, float* __restrict__ KS, int n)
{
  int bh = blockIdx.x >> 1; int dh = (blockIdx.x & 1) * 32;
  int b = bh >> 3, h = bh & 7;
  int tid = threadIdx.x, w = tid >> 6, lane = tid & 63;
  int l15 = lane & 15, lg = lane >> 4;
  float sb = stab[bh];
  __shared__ u16 ksb[32][72];
  __shared__ u16 kpT[256][40];
  __shared__ u16 vsb[32][40];
  __shared__ float dgs[32];
  fx4 kv[2][4];
  #pragma unroll
  for (int i=0;i<2;i++)
    #pragma unroll
    for (int j=0;j<4;j++)
      #pragma unroll
      for (int r=0;r<4;r++) kv[i][j][r] = 0.f;
  float ksl[4] = {0.f,0.f,0.f,0.f};
  int nchunks = (n + 31) >> 5;
  for (int c=0; c<nchunks; c++){
    int n0 = c << 5;
    for (int i = tid; i < 32*16; i += 256){
      int r = i >> 4, dq = (i & 15) * 4;
      u16x4 v = {0,0,0,0};
      if (n0 + r < n) v = *(const u16x4*)(Kb + ((size_t)b*n + n0 + r)*DMc + h*64 + dq);
      *(u16x4*)&ksb[r][dq] = v;
    }
    for (int i = tid; i < 32*8; i += 256){
      int r = i >> 3, nq4 = (i & 7) * 4;
      u16x4 v = {0,0,0,0};
      const u16* src = Vt + ((size_t)bh*64 + dh + r)*(size_t)n + n0 + nq4;
      if (n0 + nq4 + 3 < n) v = *(const u16x4*)src;
      else { for (int j=0;j<4;j++) if (n0+nq4+j < n) v[j] = src[j]; }
      *(u16x4*)&vsb[r][nq4] = v;
    }
    __syncthreads();
    { // parallel diag: 8 threads per row, shfl-reduce
      int r = tid >> 3, j = tid & 7;
      float dg = 0;
      #pragma unroll
      for (int q=0;q<8;q++){ float kd = bf2f(ksb[r][j*8+q]); dg = fmaf(kd,kd,dg); }
      dg += __shfl_down(dg,4); dg += __shfl_down(dg,2); dg += __shfl_down(dg,1);
      if (j == 0) dgs[r] = dg * 0.0625f;
    }
    __syncthreads();
    #pragma unroll
    for (int mt=0; mt<4; mt++){
      int m16 = (w*4 + mt)*16;
      #pragma unroll
      for (int nt=0; nt<2; nt++){
        fx4 a2 = {0.f,0.f,0.f,0.f};
        #pragma unroll
        for (int ks=0; ks<2; ks++){
          bfx8 af = *(const bfx8*)&ksb[nt*16 + l15][ks*32 + lg*8];
          bfx8 bf = *(const bfx8*)(projbf + (size_t)(m16 + l15)*64 + ks*32 + lg*8);
          a2 = __builtin_amdgcn_mfma_f32_16x16x32_bf16(af, bf, a2, 0, 0, 0);
        }
        #pragma unroll
        for (int r=0;r<4;r++){
          int nn = nt*16 + lg*4 + r;
          float kp = 0.f;
          if (n0 + nn < n)
            kp = (__expf(a2[r]*0.35355339059327373f - dgs[nn] - sb) + 1e-4f) * 0.0625f;
          ksl[mt] += kp;
          kpT[m16 + l15][nn] = f2bf(kp);
        }
      }
    }
    __syncthreads();
    #pragma unroll
    for (int dt=0; dt<2; dt++){
      #pragma unroll
      for (int mt=0; mt<4; mt++){
        bfx8 af = *(const bfx8*)&vsb[dt*16 + l15][lg*8];
        bfx8 bf = *(const bfx8*)&kpT[(w*4+mt)*16 + l15][lg*8];
        kv[dt][mt] = __builtin_amdgcn_mfma_f32_16x16x32_bf16(af, bf, kv[dt][mt], 0, 0, 0);
      }
    }
    __syncthreads();
  }
  if (dh == 0){
    #pragma unroll
    for (int mt=0; mt<4; mt++){
      float v = ksl[mt];
      v += __shfl_xor(v, 16);
      v += __shfl_xor(v, 32);
      if (lg == 0) KS[(size_t)bh*MFc + (w*4+mt)*16 + l15] = v;
    }
  }
  #pragma unroll
  for (int dt=0; dt<2; dt++)
    #pragma unroll
    for (int mt=0; mt<4; mt++)
      #pragma unroll
      for (int r=0;r<4;r++){
        int d = dh + dt*16 + lg*4 + r;
        int m = (w*4+mt)*16 + l15;
        KVT[((size_t)bh*64 + d)*MFc + m] = f2bf(kv[dt][mt][r]);
      }
}

// Fused Q feature-map + non-causal attention output, all-MFMA.
__global__ __launch_bounds__(256) void k_attn_mfma(const u16* __restrict__ Qb,
    const u16* __restrict__ projbf, const u16* __restrict__ KVT, const float* __restrict__ KS,
    u16* __restrict__ O, int nq)
{
  int ntile = nq >> 4;
  int rt = blockIdx.x % ntile, bh = blockIdx.x / ntile;
  int b = bh >> 3, h = bh & 7;
  int row0 = rt << 4;
  int tid = threadIdx.x, w = tid >> 6, lane = tid & 63;
  int l15 = lane & 15, lg = lane >> 4;
  __shared__ u16 qs[16][72];
  __shared__ float xds[16][264];
  __shared__ u16 qpl[16][264];
  __shared__ float dgs[16], mxs[16], dns[16];
  __shared__ float red[16][16];
  __shared__ float kss[256];
  for (int i = tid; i < 16*16; i += 256){
    int r = i >> 4, dq = (i & 15)*4;
    *(u16x4*)&qs[r][dq] = *(const u16x4*)(Qb + ((size_t)b*nq + row0 + r)*DMc + h*64 + dq);
  }
  kss[tid] = KS[(size_t)bh*MFc + tid];
  __syncthreads();
  if (tid < 16){
    float dg = 0;
    #pragma unroll 16
    for (int d=0;d<64;d++){ float q = bf2f(qs[tid][d]); dg = fmaf(q,q,dg); }
    dgs[tid] = dg * 0.0625f;
  }
  #pragma unroll
  for (int mt=0; mt<4; mt++){
    int m16 = (w*4+mt)*16;
    fx4 a2 = {0.f,0.f,0.f,0.f};
    #pragma unroll
    for (int ks=0; ks<2; ks++){
      bfx8 af = *(const bfx8*)&qs[l15][ks*32 + lg*8];
      bfx8 bf = *(const bfx8*)(projbf + (size_t)(m16+l15)*64 + ks*32 + lg*8);
      a2 = __builtin_amdgcn_mfma_f32_16x16x32_bf16(af, bf, a2, 0, 0, 0);
    }
    #pragma unroll
    for (int r=0;r<4;r++)
      xds[lg*4+r][m16+l15] = a2[r]*0.35355339059327373f;
  }
  __syncthreads();
  { int r = tid >> 4, s = tid & 15;
    float mx = -1e30f;
    #pragma unroll
    for (int j=0;j<16;j++) mx = fmaxf(mx, xds[r][s*16+j]);
    red[r][s] = mx; }
  __syncthreads();
  if (tid < 16){
    float mx = -1e30f;
    #pragma unroll
    for (int j=0;j<16;j++) mx = fmaxf(mx, red[tid][j]);
    mxs[tid] = mx;
  }
  __syncthreads();
  { int r = tid >> 4, s = tid & 15;
    float dg = dgs[r], mx = mxs[r], pd = 0;
    #pragma unroll
    for (int j=0;j<16;j++){
      int m = s*16+j;
      float v = (__expf(xds[r][m] - dg - mx) + 1e-4f)*0.0625f;
      qpl[r][m] = f2bf(v);
      pd = fmaf(v, kss[m], pd);
    }
    red[r][s] = pd; }
  __syncthreads();
  if (tid < 16){
    float s = 0;
    #pragma unroll
    for (int j=0;j<16;j++) s += red[tid][j];
    dns[tid] = 1.0f / s;
  }
  __syncthreads();
  fx4 a2 = {0.f,0.f,0.f,0.f};
  #pragma unroll
  for (int ks=0; ks<8; ks++){
    bfx8 af = *(const bfx8*)&qpl[l15][ks*32 + lg*8];
    bfx8 bf = *(const bfx8*)(KVT + ((size_t)bh*64 + w*16 + l15)*MFc + ks*32 + lg*8);
    a2 = __builtin_amdgcn_mfma_f32_16x16x32_bf16(af, bf, a2, 0, 0, 0);
  }
  #pragma unroll
  for (int r=0;r<4;r++){
    int row = lg*4 + r;
    O[((size_t)b*nq + row0 + row)*DMc + h*64 + w*16 + l15] = f2bf(a2[r]*dns[row]);
  }
}

// Feature-map rows -> P[bh][n][256] bf16 (for causal attention), all-MFMA.
template<int ISQ>
__global__ __launch_bounds__(256) void k_fmap_mfma(const u16* __restrict__ Xb,
    const u16* __restrict__ projbf, const float* __restrict__ stab,
    u16* __restrict__ P, int n)
{
  int ntile = n >> 4;
  int rt = blockIdx.x % ntile, bh = blockIdx.x / ntile;
  int b = bh >> 3, h = bh & 7;
  int row0 = rt << 4;
  int tid = threadIdx.x, w = tid >> 6, lane = tid & 63;
  int l15 = lane & 15, lg = lane >> 4;
  __shared__ u16 qs[16][72];
  __shared__ float xds[16][264];
  __shared__ float dgs[16], mxs[16];
  __shared__ float red[16][16];
  for (int i = tid; i < 16*16; i += 256){
    int r = i >> 4, dq = (i & 15)*4;
    *(u16x4*)&qs[r][dq] = *(const u16x4*)(Xb + ((size_t)b*n + row0 + r)*DMc + h*64 + dq);
  }
  __syncthreads();
  if (tid < 16){
    float dg = 0;
    #pragma unroll 16
    for (int d=0;d<64;d++){ float q = bf2f(qs[tid][d]); dg = fmaf(q,q,dg); }
    dgs[tid] = dg * 0.0625f;
  }
  #pragma unroll
  for (int mt=0; mt<4; mt++){
    int m16 = (w*4+mt)*16;
    fx4 a2 = {0.f,0.f,0.f,0.f};
    #pragma unroll
    for (int ks=0; ks<2; ks++){
      bfx8 af = *(const bfx8*)&qs[l15][ks*32 + lg*8];
      bfx8 bf = *(const bfx8*)(projbf + (size_t)(m16+l15)*64 + ks*32 + lg*8);
      a2 = __builtin_amdgcn_mfma_f32_16x16x32_bf16(af, bf, a2, 0, 0, 0);
    }
    #pragma unroll
    for (int r=0;r<4;r++)
      xds[lg*4+r][m16+l15] = a2[r]*0.35355339059327373f;
  }
  __syncthreads();
  if (ISQ){
    { int r = tid >> 4, s = tid & 15;
      float mx = -1e30f;
      #pragma unroll
      for (int j=0;j<16;j++) mx = fmaxf(mx, xds[r][s*16+j]);
      red[r][s] = mx; }
    __syncthreads();
    if (tid < 16){
      float mx = -1e30f;
      #pragma unroll
      for (int j=0;j<16;j++) mx = fmaxf(mx, red[tid][j]);
      mxs[tid] = mx;
    }
    __syncthreads();
  }
  { int r = tid >> 4, s = tid & 15;
    float sv = ISQ ? mxs[r] : stab[bh];
    float dg = dgs[r];
    u16* dst = P + ((size_t)bh*n + row0 + r)*MFc;
    #pragma unroll
    for (int j=0;j<16;j++){
      int m = s*16+j;
      dst[m] = f2bf((__expf(xds[r][m] - dg - sv) + 1e-4f)*0.0625f);
    }
  }
}

// Causal attention, all-MFMA. P_Q,P_K: [bh][n][256] bf16; Vt: [bh][64][n] bf16.
__global__ __launch_bounds__(256) void k_causal_mfma(const u16* __restrict__ PQ,
    const u16* __restrict__ PK, const u16* __restrict__ Vt, u16* __restrict__ O, int n)
{
  int ntile = n >> 4;                       // 9 for n=144
  int it = blockIdx.x % ntile, bh = blockIdx.x / ntile;
  int b = bh >> 3, h = bh & 7;
  int row0 = it << 4;
  int tid = threadIdx.x, w = tid >> 6, lane = tid & 63;
  int l15 = lane & 15, lg = lane >> 4;
  __shared__ u16 qp[16][264];
  __shared__ float sf[16][168];
  __shared__ u16 sb[16][168];
  __shared__ u16 vt[64][168];
  __shared__ float dns[16];
  __shared__ float red[16][16];
  #pragma unroll
  for (int p=0;p<4;p++){
    int idx = tid + (p<<8);
    int r = idx >> 6, c4 = (idx & 63)*4;
    *(u16x4*)&qp[r][c4] = *(const u16x4*)(PQ + ((size_t)bh*n + row0 + r)*MFc + c4);
  }
  for (int i = tid; i < 64*40; i += 256){
    int r = i / 40, c4 = (i % 40)*4;
    u16x4 v = {0,0,0,0};
    if (c4 < 144) v = *(const u16x4*)(Vt + ((size_t)bh*64 + r)*(size_t)n + c4);
    *(u16x4*)&vt[r][c4] = v;
  }
  { int r = tid >> 4, c = 144 + (tid & 15);
    sb[r][c] = 0; sf[r][c] = 0.f; }
  __syncthreads();
  for (int jt = w; jt < 9; jt += 4){
    fx4 a2 = {0.f,0.f,0.f,0.f};
    #pragma unroll
    for (int ks=0; ks<8; ks++){
      bfx8 af = *(const bfx8*)&qp[l15][ks*32 + lg*8];
      bfx8 bf = *(const bfx8*)(PK + ((size_t)bh*n + jt*16 + l15)*MFc + ks*32 + lg*8);
      a2 = __builtin_amdgcn_mfma_f32_16x16x32_bf16(af, bf, a2, 0, 0, 0);
    }
    int jg = jt*16 + l15;
    #pragma unroll
    for (int r=0;r<4;r++){
      int il = lg*4 + r;
      float v = (jg <= row0 + il) ? a2[r] : 0.f;
      sf[il][jg] = v;
      sb[il][jg] = f2bf(v);
    }
  }
  __syncthreads();
  { int r = tid >> 4, s = tid & 15;
    float pd = 0;
    #pragma unroll
    for (int q=0;q<9;q++) pd += sf[r][s*9 + q];
    red[r][s] = pd; }
  __syncthreads();
  if (tid < 16){
    float s = 0;
    #pragma unroll
    for (int j=0;j<16;j++) s += red[tid][j];
    dns[tid] = 1.0f / (s + 1e-6f);
  }
  __syncthreads();
  fx4 a2 = {0.f,0.f,0.f,0.f};
  #pragma unroll
  for (int ks=0; ks<5; ks++){
    bfx8 af = *(const bfx8*)&sb[l15][ks*32 + lg*8];
    bfx8 bf = *(const bfx8*)&vt[w*16 + l15][ks*32 + lg*8];
    a2 = __builtin_amdgcn_mfma_f32_16x16x32_bf16(af, bf, a2, 0, 0, 0);
  }
  #pragma unroll
  for (int r=0;r<4;r++){
    int il = lg*4 + r;
    O[((size_t)b*n + row0 + il)*DMc + h*64 + w*16 + l15] = f2bf(a2[r]*dns[il]);
  }
}

// LayerNorm over rows of 512, templated on input/residual/output bf16-ness.
template<int ABF, int RBF, int OBF>
__global__ __launch_bounds__(128) void k_ln(const void* __restrict__ Ap, const void* __restrict__ Rp,
    const float* __restrict__ g, const float* __restrict__ beta, void* __restrict__ outp)
{
  size_t row = blockIdx.x; int t = threadIdx.x;
  float4 v;
  if (ABF){
    u16x4 a = *((const u16x4*)Ap + row*(DMc/4) + t);
    v.x = bf2f(a.x); v.y = bf2f(a.y); v.z = bf2f(a.z); v.w = bf2f(a.w);
  } else {
    v = *((const float4*)Ap + row*(DMc/4) + t);
  }
  if (Rp){
    if (RBF){
      u16x4 wv = *((const u16x4*)Rp + row*(DMc/4) + t);
      v.x += bf2f(wv.x); v.y += bf2f(wv.y); v.z += bf2f(wv.z); v.w += bf2f(wv.w);
    } else {
      float4 wv = *((const float4*)Rp + row*(DMc/4) + t);
      v.x += wv.x; v.y += wv.y; v.z += wv.z; v.w += wv.w;
    }
  }
  __shared__ float red[2];
  float s = v.x+v.y+v.z+v.w;
  for (int o=32;o;o>>=1) s += __shfl_xor(s,o);
  if ((t&63)==0) red[t>>6]=s;
  __syncthreads();
  float mu = (red[0]+red[1]) * (1.0f/DMc);
  float dx=v.x-mu, dy=v.y-mu, dz=v.z-mu, dw=v.w-mu;
  float qq = dx*dx+dy*dy+dz*dz+dw*dw;
  __syncthreads();
  for (int o=32;o;o>>=1) qq += __shfl_xor(qq,o);
  if ((t&63)==0) red[t>>6]=qq;
  __syncthreads();
  float var = (red[0]+red[1]) * (1.0f/DMc);
  float rs = 1.0f / sqrtf(var + 1e-5f);
  const float4 g4 = *(const float4*)(g + t*4);
  const float4 b4 = *(const float4*)(beta + t*4);
  float ox = dx*rs*g4.x + b4.x;
  float oy = dy*rs*g4.y + b4.y;
  float oz = dz*rs*g4.z + b4.z;
  float ow = dw*rs*g4.w + b4.w;
  if (OBF){
    u16x4 o4; o4.x=f2bf(ox); o4.y=f2bf(oy); o4.z=f2bf(oz); o4.w=f2bf(ow);
    *((u16x4*)outp + row*(DMc/4) + t) = o4;
  } else {
    float4 o4; o4.x=ox; o4.y=oy; o4.z=oz; o4.w=ow;
    *((float4*)outp + row*(DMc/4) + t) = o4;
  }
}

// final projection + de-standardize + slice last 96
__global__ __launch_bounds__(64) void k_final(const float* __restrict__ X, const float* __restrict__ pw,
   const float* __restrict__ pb, const float* __restrict__ means, const float* __restrict__ stdev,
   float* __restrict__ outp)
{
  int blk = blockIdx.x; int lo = blk % PREDc; int b = blk / PREDc;
  int l = lo + (LDc - PREDc);
  int t = threadIdx.x;
  float acc[7];
  #pragma unroll
  for (int c=0;c<7;c++) acc[c]=0;
  const float* xr = X + ((size_t)b*LDc + l)*DMc;
  for (int d=t; d<DMc; d+=64){
    float xv = xr[d];
    #pragma unroll
    for (int c=0;c<7;c++) acc[c] = fmaf(xv, pw[d*7+c], acc[c]);
  }
  #pragma unroll
  for (int c=0;c<7;c++){
    float s = acc[c];
    for (int o=32;o;o>>=1) s += __shfl_xor(s,o);
    if (t==0)
      outp[((size_t)b*PREDc + lo)*7 + c] = (s + pb[c]) * stdev[b*7+c] + means[b*7+c];
  }
}

// =====================================================================
extern "C" void kernel_launch(void* const* d_in, const int* in_sizes, int n_in,
                              void* d_out, int out_size, void* d_ws, size_t ws_size,
                              hipStream_t stream)
{
  (void)in_sizes; (void)n_in;
  const float* x_enc        = (const float*)d_in[0];
  const float* x_mark_enc   = (const float*)d_in[1];
  const float* x_dec        = (const float*)d_in[2];
  const float* x_mark_dec   = (const float*)d_in[3];
  const float* emb_conv_enc = (const float*)d_in[4];
  const float* emb_time_enc = (const float*)d_in[5];
  const float* emb_conv_dec = (const float*)d_in[6];
  const float* emb_time_dec = (const float*)d_in[7];
  const float* enc_Wq = (const float*)d_in[8];
  const float* enc_Wk = (const float*)d_in[9];
  const float* enc_Wv = (const float*)d_in[10];
  const float* enc_Wo = (const float*)d_in[11];
  const float* enc_bo = (const float*)d_in[12];
  const float* enc_ff1 = (const float*)d_in[13];
  const float* enc_b1  = (const float*)d_in[14];
  const float* enc_ff2 = (const float*)d_in[15];
  const float* enc_b2  = (const float*)d_in[16];
  const float* enc_ln_g = (const float*)d_in[17];
  const float* enc_ln_b = (const float*)d_in[18];
  const float* enc_fg = (const float*)d_in[19];
  const float* enc_fb = (const float*)d_in[20];
  const float* dec_sWq = (const float*)d_in[21];
  const float* dec_sWk = (const float*)d_in[22];
  const float* dec_sWv = (const float*)d_in[23];
  const float* dec_sWo = (const float*)d_in[24];
  const float* dec_sbo = (const float*)d_in[25];
  const float* dec_cWq = (const float*)d_in[26];
  const float* dec_cWk = (const float*)d_in[27];
  const float* dec_cWv = (const float*)d_in[28];
  const float* dec_cWo = (const float*)d_in[29];
  const float* dec_cbo = (const float*)d_in[30];
  const float* dec_ff1 = (const float*)d_in[31];
  const float* dec_b1  = (const float*)d_in[32];
  const float* dec_ff2 = (const float*)d_in[33];
  const float* dec_b2  = (const float*)d_in[34];
  const float* dec_ln_g = (const float*)d_in[35];
  const float* dec_ln_b = (const float*)d_in[36];
  const float* dec_fg = (const float*)d_in[37];
  const float* dec_fb = (const float*)d_in[38];
  const float* proj_w = (const float*)d_in[39];
  const float* proj_b = (const float*)d_in[40];
  float* outp = (float*)d_out;
  float* W = (float*)d_ws;

  // ---- workspace carve (float units). Total ~= 123 MB ----
  size_t o = 0;
  #define ALLOCF(nm, n) size_t nm = o; o += (((size_t)(n)) + 63) & ~(size_t)63;
  ALLOCF(o_proj, 4*MFc*DHc)
  ALLOCF(o_projbf, 2*MFc*DHc)            // 4 sets of bf16 proj (u16)
  ALLOCF(o_means, BB*7)
  ALLOCF(o_std,   BB*7)
  ALLOCF(o_rmE, (size_t)BHc*LEc)
  ALLOCF(o_rmD, (size_t)BHc*LDc)
  ALLOCF(o_stab, BHc)
  ALLOCF(o_KS, KSn)
  ALLOCF(o_PE, (size_t)LEc*DMc)          // sinusoidal PE table (dec = rows 0..143)
  ALLOCF(o_Dx1, (size_t)NDc*DMc)         // decoder x1 (bf16 in first half; survives cross)
  ALLOCF(o_WT, 5242880)                  // 10,485,760 bf16 weights
  ALLOCF(o_Xb, (size_t)NEc*DMc)          // residual stream f32
  ALLOCF(o_X1, (size_t)NEc*DMc)          // x1bf + attnbf (u16 halves) / Vt+KVT / dec f32 slots
  ALLOCF(o_U,  11796480)                 // 23,592,960 u16 union region
  #undef ALLOCF
  size_t needed_bytes = o * sizeof(float);
  if (ws_size < needed_bytes){
    k_zero<<<(out_size+255)/256, 256, 0, stream>>>(outp, out_size);
    return;
  }

  float* Xb  = W + o_Xb;
  float* X1  = W + o_X1;
  float* KS  = W + o_KS;
  float* PE  = W + o_PE;
  float* rmE = W + o_rmE;
  float* rmD = W + o_rmD;
  float* stb = W + o_stab;
  u16*  WTb = (u16*)(W + o_WT);
  u16*  Uh  = (u16*)(W + o_U);
  u16*  PJB = (u16*)(W + o_projbf);

  const size_t NEu = (size_t)NEc*DMc;      // 5,898,240
  const size_t NDu = (size_t)NDc*DMc;      // 1,179,648
  // encoder bf16 slots
  u16* Tq = Uh;            u16* Tk = Uh + NEu;
  u16* Tv = Uh + 2*NEu;    u16* Oe = Uh + 3*NEu;
  u16* FFb = Uh;                                   // full-M FF intermediate (aliases all slots)
  // Vt (full 128 bh) + KVT live in X1 during kv/attn phases
  u16*   VtU  = (u16*)X1;                          // 5,898,240 u16
  u16*   KVTu = (u16*)(X1 + 2949120);              // 2,097,152 u16
  // encoder bf16 x1/attn slots (X1 region as u16 halves)
  u16*   x1bf   = (u16*)X1;                        // [0, NEu)
  u16*   attnbf = (u16*)X1 + NEu;                  // [NEu, 2*NEu)
  // decoder phase aliases (in U)
  u16* dTq = Uh;           u16* dTk = Uh + NDu;
  u16* dTv = Uh + 2*NDu;   u16* dOd = Uh + 3*NDu;
  u16* PQb = Uh + 4*NDu;                            // [128][144][256] bf16
  u16* PKb = PQb + (size_t)BHc*LDc*MFc;             // + 4,718,592
  u16* VtD = PKb + (size_t)BHc*LDc*MFc;             // [128][64][144] bf16
  // cross phase aliases
  u16* cTk = Uh;           u16* cTv = Uh + NEu;
  u16* dTq2 = Uh + 2*NEu;  u16* cOd = Uh + 2*NEu + NDu;
  u16* dFF = Uh;                                   // 2304x2048
  // decoder f32 slots in X1 (dead during kv phases)
  float* DX  = X1 + 0*NDu;
  float* Da  = X1 + 1*NDu;
  float* Dx2 = X1 + 2*NDu;
  float* Dy  = X1 + 3*NDu;
  u16* dAttnbf = (u16*)Da;                         // bf16 self-attn out (first half of Da slot)
  u16* Dx1bf   = (u16*)(W + o_Dx1);                // bf16 x1 (own carve, survives cross)
  u16* Dx2bf   = (u16*)Dx2;                        // bf16 x2 (first half of Dx2 slot)

  // ---- host: exact numpy ORF projection matrices, upload ----
  static float h_proj[4*MFc*DHc];
  build_all_proj(h_proj);
  hipMemcpyAsync(W + o_proj, h_proj, sizeof(h_proj), hipMemcpyHostToDevice, stream);
  k_projbf<<<(4*MFc*DHc)/256, 256, 0, stream>>>(W + o_proj, PJB, 4*MFc*DHc);
  const u16* pb_enc0  = PJB + 0*MFc*DHc;
  const u16* pb_enc1  = PJB + 1*MFc*DHc;
  const u16* pb_self  = PJB + 2*MFc*DHc;
  const u16* pb_cross = PJB + 3*MFc*DHc;

  // ---- PE table ----
  k_petab<<<(LEc*DMc)/256, 256, 0, stream>>>(PE);

  // ---- device: transpose+cast all GEMM weights to bf16 WT[N][K] ----
  size_t wto = 0;
  auto xpose = [&](const float* Wsrc, int K, int N) -> const u16* {
    u16* dst = WTb + wto; wto += (size_t)K*N;
    k_wtr<<<dim3(K/32, N/32), 256, 0, stream>>>(Wsrc, dst, K, N);
    return dst;
  };
  const u16 *wQ[2], *wK[2], *wV[2], *wO[2], *wF1[2], *wF2[2];
  for (int i=0;i<2;i++){
    wQ[i]  = xpose(enc_Wq + (size_t)i*DMc*DMc, DMc, DMc);
    wK[i]  = xpose(enc_Wk + (size_t)i*DMc*DMc, DMc, DMc);
    wV[i]  = xpose(enc_Wv + (size_t)i*DMc*DMc, DMc, DMc);
    wO[i]  = xpose(enc_Wo + (size_t)i*DMc*DMc, DMc, DMc);
    wF1[i] = xpose(enc_ff1 + (size_t)i*DMc*FFc, DMc, FFc);
    wF2[i] = xpose(enc_ff2 + (size_t)i*FFc*DMc, FFc, DMc);
  }
  const u16* wsQ = xpose(dec_sWq, DMc, DMc);
  const u16* wsK = xpose(dec_sWk, DMc, DMc);
  const u16* wsV = xpose(dec_sWv, DMc, DMc);
  const u16* wsO = xpose(dec_sWo, DMc, DMc);
  const u16* wcQ = xpose(dec_cWq, DMc, DMc);
  const u16* wcK = xpose(dec_cWk, DMc, DMc);
  const u16* wcV = xpose(dec_cWv, DMc, DMc);
  const u16* wcO = xpose(dec_cWo, DMc, DMc);
  const u16* wdF1 = xpose(dec_ff1, DMc, FFc);
  const u16* wdF2 = xpose(dec_ff2, FFc, DMc);

  // non-causal K-side chain: rowmax(MFMA) -> stab -> Vt -> fused MFMA kv
  auto kv_chain = [&](const u16* Kbuf, const u16* Vbuf, const u16* pjb){
    k_rowmax_mfma<<<BHc*(LEc/16), 256, 0, stream>>>(Kbuf, pjb, rmE, LEc);
    k_stab<<<BHc, 256, 0, stream>>>(rmE, stb, LEc);
    k_vtr<<<BHc*(LEc/16), 256, 0, stream>>>(Vbuf, VtU, LEc);
    k_kvfull<<<BHc*2, 256, 0, stream>>>(Kbuf, VtU, pjb, stb, KVTu, KS, LEc);
  };

  // ---- RevIN stats + encoder embed ----
  k_meanstd<<<BB*7, 64, 0, stream>>>(x_enc, W+o_means, W+o_std);
  k_embed<<<(BB*LEc*DMc)/256, 256, 0, stream>>>(x_enc, x_mark_enc, emb_conv_enc, emb_time_enc,
                                                PE, W+o_means, W+o_std, LEc, 1, Xb);

  // ---- encoder layers ----
  for (int i=0;i<2;i++){
    const float* bo = enc_bo + (size_t)i*DMc;
    const float* b1 = enc_b1  + (size_t)i*FFc;
    const float* b2 = enc_b2  + (size_t)i*DMc;
    const float* g0 = enc_ln_g + (size_t)(i*2+0)*DMc;
    const float* e0 = enc_ln_b + (size_t)(i*2+0)*DMc;
    const float* g1 = enc_ln_g + (size_t)(i*2+1)*DMc;
    const float* e1 = enc_ln_b + (size_t)(i*2+1)*DMc;
    const u16*   pjb = (i==0) ? pb_enc0 : pb_enc1;

    gemm_bf(Xb, wQ[i], nullptr, Tq, NEc, DMc, DMc, 0,1,0, stream);
    gemm_bf(Xb, wK[i], nullptr, Tk, NEc, DMc, DMc, 0,1,0, stream);
    gemm_bf(Xb, wV[i], nullptr, Tv, NEc, DMc, DMc, 0,1,0, stream);
    kv_chain(Tk, Tv, pjb);
    k_attn_mfma<<<BHc*(LEc/16), 256, 0, stream>>>(Tq, pjb, KVTu, KS, Oe, LEc);
    gemm_bf(Oe, wO[i], bo, attnbf, NEc, DMc, DMc, 1,1,0, stream);        // attn out bf16
    k_ln<1,0,1><<<NEc, 128, 0, stream>>>(attnbf, Xb, g0, e0, x1bf);      // x1 -> bf16
    gemm_bf(x1bf, wF1[i], b1, FFb, NEc, FFc, DMc, 1,1,1, stream);        // gelu -> bf16
    gemm_bf(FFb, wF2[i], b2, Xb, NEc, DMc, FFc, 1,0,0, stream);          // y -> Xb f32
    k_ln<0,1,0><<<NEc, 128, 0, stream>>>(Xb, x1bf, g1, e1, Xb);          // enc = LN(y+x1)
  }
  k_ln<0,0,0><<<NEc, 128, 0, stream>>>(Xb, nullptr, enc_fg, enc_fb, Xb); // final enc norm

  // ---- decoder ----
  k_embed<<<(BB*LDc*DMc)/256, 256, 0, stream>>>(x_dec, x_mark_dec, emb_conv_dec, emb_time_dec,
                                                PE, W+o_means, W+o_std, LDc, 0, DX);
  // self (causal), all-MFMA
  gemm_bf(DX, wsQ, nullptr, dTq, NDc, DMc, DMc, 0,1,0, stream);
  gemm_bf(DX, wsK, nullptr, dTk, NDc, DMc, DMc, 0,1,0, stream);
  gemm_bf(DX, wsV, nullptr, dTv, NDc, DMc, DMc, 0,1,0, stream);
  k_rowmax_mfma<<<BHc*(LDc/16), 256, 0, stream>>>(dTk, pb_self, rmD, LDc);
  k_stab<<<BHc, 256, 0, stream>>>(rmD, stb, LDc);
  k_fmap_mfma<1><<<BHc*(LDc/16), 256, 0, stream>>>(dTq, pb_self, nullptr, PQb, LDc);
  k_fmap_mfma<0><<<BHc*(LDc/16), 256, 0, stream>>>(dTk, pb_self, stb, PKb, LDc);
  k_vtr<<<BHc*(LDc/16), 256, 0, stream>>>(dTv, VtD, LDc);
  k_causal_mfma<<<BHc*(LDc/16), 256, 0, stream>>>(PQb, PKb, VtD, dOd, LDc);
  gemm_bf(dOd, wsO, dec_sbo, dAttnbf, NDc, DMc, DMc, 1,1,0, stream);
  k_ln<1,0,1><<<NDc, 128, 0, stream>>>(dAttnbf, DX, dec_ln_g + 0*DMc, dec_ln_b + 0*DMc, Dx1bf); // x1 bf16

  // cross
  gemm_bf(Dx1bf, wcQ, nullptr, dTq2, NDc, DMc, DMc, 1,1,0, stream);
  gemm_bf(Xb,  wcK, nullptr, cTk,  NEc, DMc, DMc, 0,1,0, stream);
  gemm_bf(Xb,  wcV, nullptr, cTv,  NEc, DMc, DMc, 0,1,0, stream);
  kv_chain(cTk, cTv, pb_cross);
  k_attn_mfma<<<BHc*(LDc/16), 256, 0, stream>>>(dTq2, pb_cross, KVTu, KS, cOd, LDc);
  gemm_bf(cOd, wcO, dec_cbo, Da, NDc, DMc, DMc, 1,0,0, stream);
  k_ln<0,1,1><<<NDc, 128, 0, stream>>>(Da, Dx1bf, dec_ln_g + 1*DMc, dec_ln_b + 1*DMc, Dx2bf);  // x2 bf16

  // FF + final norms + projection
  gemm_bf(Dx2bf, wdF1, dec_b1, dFF, NDc, FFc, DMc, 1,1,1, stream);
  gemm_bf(dFF, wdF2, dec_b2, Dy, NDc, DMc, FFc, 1,0,0, stream);
  k_ln<0,1,0><<<NDc, 128, 0, stream>>>(Dy, Dx2bf, dec_ln_g + 2*DMc, dec_ln_b + 2*DMc, Da);
  k_ln<0,0,0><<<NDc, 128, 0, stream>>>(Da, nullptr, dec_fg, dec_fb, Da);
  k_final<<<BB*PREDc, 64, 0, stream>>>(Da, proj_w, proj_b, W+o_means, W+o_std, outp);
}